// Round 1
// 2952.742 us; speedup vs baseline: 1.0656x; 1.0656x over previous
//
#include <hip/hip_runtime.h>
#include <hip/hip_bf16.h>
#include <cstdint>
#include <cmath>
#include <vector>
#include <algorithm>
#include <numeric>

// ---------------------------------------------------------------------------
// LapSWD loss. RNG = exact JAX partitionable threefry (verified absmax 0.0).
// R6: sortdiff now sorts BOTH columns (proj1/proj2) in one interleaved pass:
//  - wave-level bitonic runs the two independent compare-exchange networks
//    back-to-back per stage (2x ILP on the shuffle latency chains),
//  - sorted column A is held in 16 VGPRs while column B does its merge-path
//    rounds through the shared 64KB LDS buffer (kills the 32MB global
//    write-back + re-read of phase 0),
//  - merge-path i1 co-rank is taken from lane t+1's i0 via shfl_down
//    (halves the dependent binary-search chains).
// __launch_bounds__(1024, 8) keeps VGPR<=64 so 2 blocks/CU still fit.
// ---------------------------------------------------------------------------

__constant__ float KW[5] = {0.0625f, 0.25f, 0.375f, 0.25f, 0.0625f};

struct RC { unsigned int rc[128]; };

// ---- threefry2x32 block cipher, exact JAX/XLA schedule ----
__host__ __device__ inline void tf2x32(uint32_t k0, uint32_t k1,
                                       uint32_t x0, uint32_t x1,
                                       uint32_t& o0, uint32_t& o1) {
  uint32_t k2 = k0 ^ k1 ^ 0x1BD11BDAu;
  x0 += k0; x1 += k1;
#define TFR(r) { x0 += x1; x1 = (x1 << r) | (x1 >> (32 - r)); x1 ^= x0; }
  TFR(13) TFR(15) TFR(26) TFR(6)   x0 += k1; x1 += k2 + 1u;
  TFR(17) TFR(29) TFR(16) TFR(24)  x0 += k2; x1 += k0 + 2u;
  TFR(13) TFR(15) TFR(26) TFR(6)   x0 += k0; x1 += k1 + 3u;
  TFR(17) TFR(29) TFR(16) TFR(24)  x0 += k1; x1 += k2 + 4u;
  TFR(13) TFR(15) TFR(26) TFR(6)   x0 += k2; x1 += k0 + 5u;
#undef TFR
  o0 = x0; o1 = x1;
}

// ---- host tables (pure constants; computed once at library load) ----
struct HostTables {
  RC rcs[5];
  uint32_t kp0[5], kp1[5];
  HostTables() {
    static const int Hs[5] = {256, 128, 64, 32, 16};
    for (int l = 0; l < 5; ++l) {
      uint32_t f0, f1;
      tf2x32(0u, 42u, 0u, (uint32_t)l, f0, f1);  // fold_in(key(42), l)
      uint32_t ik0, ik1;
      tf2x32(f0, f1, 0u, 0u, ik0, ik1);          // k_idx = split[0]
      tf2x32(f0, f1, 0u, 1u, kp0[l], kp1[l]);    // k_proj = split[1]
      int Wm6 = Hs[l] - 6;
      int n = Wm6 * Wm6;
      int nd = n < 128 ? n : 128;
      std::vector<int> perm(n);
      std::iota(perm.begin(), perm.end(), 0);
      int rounds = (int)std::ceil(3.0 * std::log((double)n) / std::log(4294967295.0));
      uint32_t key0 = ik0, key1 = ik1;
      std::vector<uint32_t> bits(n);
      std::vector<int> ord(n), tmp(n);
      for (int r = 0; r < rounds; ++r) {
        uint32_t nk0, nk1, s0, s1;
        tf2x32(key0, key1, 0u, 0u, nk0, nk1);
        tf2x32(key0, key1, 0u, 1u, s0, s1);
        key0 = nk0; key1 = nk1;
        for (int tt = 0; tt < n; ++tt) {
          uint32_t o0, o1;
          tf2x32(s0, s1, 0u, (uint32_t)tt, o0, o1);
          bits[tt] = o0 ^ o1;
        }
        std::iota(ord.begin(), ord.end(), 0);
        std::stable_sort(ord.begin(), ord.end(),
                         [&](int A, int B) { return bits[A] < bits[B]; });
        for (int i2 = 0; i2 < n; ++i2) tmp[i2] = perm[ord[i2]];
        perm.swap(tmp);
      }
      for (int d = 0; d < 128; ++d) {
        int vv = (d < nd) ? perm[d] : 0;
        rcs[l].rc[d] = ((uint32_t)(vv / Wm6) << 16) | (uint32_t)(vv % Wm6);
      }
    }
  }
};
static const HostTables g_tbl;

__device__ inline float erfinv_f(float x) {
  float w = -log1pf(-x * x);
  float p;
  if (w < 5.0f) {
    w = w - 2.5f;
    p = 2.81022636e-08f;
    p = fmaf(p, w, 3.43273939e-07f);
    p = fmaf(p, w, -3.5233877e-06f);
    p = fmaf(p, w, -4.39150654e-06f);
    p = fmaf(p, w, 0.00021858087f);
    p = fmaf(p, w, -0.00125372503f);
    p = fmaf(p, w, -0.00417768164f);
    p = fmaf(p, w, 0.246640727f);
    p = fmaf(p, w, 1.50140941f);
  } else {
    w = sqrtf(w) - 3.0f;
    p = -0.000200214257f;
    p = fmaf(p, w, 0.000100950558f);
    p = fmaf(p, w, 0.00134934322f);
    p = fmaf(p, w, -0.00367342844f);
    p = fmaf(p, w, 0.00573950773f);
    p = fmaf(p, w, -0.0076224613f);
    p = fmaf(p, w, 0.00943887047f);
    p = fmaf(p, w, 1.00167406f);
    p = fmaf(p, w, 2.83297682f);
  }
  return p * x;
}

__device__ inline float bits_to_normal(uint32_t b) {
  union { uint32_t u; float f; } cv;
  cv.u = (b >> 9) | 0x3f800000u;
  float f = cv.f - 1.0f;
  const float lo = -0.99999994f;
  const float span = 1.0f - lo;
  float u = fmaxf(lo, __fadd_rn(__fmul_rn(f, span), lo));
  return 1.41421356237f * erfinv_f(u);
}

// ---- kernels ----

__global__ void init_kernel(float* m) {
  int i = threadIdx.x;
  if (i < 128) m[i] = 0.f;
}

__global__ __launch_bounds__(256) void down_kernel(
    const float* __restrict__ in, float* __restrict__ out,
    int H, int W, int total) {
  int idx = blockIdx.x * 256 + threadIdx.x;
  if (idx >= total) return;
  int Wo = W >> 1, Ho = H >> 1;
  int ox = idx % Wo;
  int t = idx / Wo;
  int oy = t % Ho;
  int bc = t / Ho;
  const float* src = in + (size_t)bc * H * W;
  float s = 0.f;
#pragma unroll
  for (int u = 0; u < 5; ++u) {
    int y = 2 * oy + u - 2;
    if (y < 0 || y >= H) continue;
    const float* r = src + (size_t)y * W;
#pragma unroll
    for (int v = 0; v < 5; ++v) {
      int x = 2 * ox + v - 2;
      if (x < 0 || x >= W) continue;
      s += KW[u] * KW[v] * r[x];
    }
  }
  out[idx] = s;
}

__global__ void randgen_kernel(float* __restrict__ rnd, uint32_t k0, uint32_t k1) {
  int t = blockIdx.x * 256 + threadIdx.x;  // grid covers 81920
  const int total = 75264;                 // 147*512
  if (t < total) {
    uint32_t o0, o1;
    tf2x32(k0, k1, 0u, (uint32_t)t, o0, o1);
    rnd[t] = bits_to_normal(o0 ^ o1);
  }
}

// extract + per-channel stats (sum, sumsq) fused
__global__ __launch_bounds__(256) void extract_kernel(
    const float* __restrict__ g, const float* __restrict__ gn,
    float* __restrict__ p, float* __restrict__ st, RC rcs,
    int H, int nd, int useLap, int total) {
  __shared__ float ls[6];
  if (threadIdx.x < 6) ls[threadIdx.x] = 0.f;
  __syncthreads();
  int idx = blockIdx.x * 256 + threadIdx.x;
  if (idx < total) {                    // total = M*160
    int col = idx % 160;
    if (col < 147) {
      int row = idx / 160;
      int d = row % nd, b = row / nd;
      int c = col / 49, uv = col % 49, u = uv / 7, v = uv % 7;
      unsigned rc = rcs.rc[d];
      int y = (int)(rc >> 16) + u;
      int x = (int)(rc & 0xffffu) + v;
      const float* gc = g + ((size_t)(b * 3 + c)) * H * H;
      float val = gc[(size_t)y * H + x];
      if (useLap) {
        int H2 = H >> 1;
        const float* gnc = gn + ((size_t)(b * 3 + c)) * H2 * H2;
        int h = y >> 1, w = x >> 1;
        int yo = y & 1, xo = x & 1;
        float rw0 = (y >= 2) ? (yo ? 0.0625f : 0.3125f) : 0.f;
        float rw2 = (y <= H - 3) ? (yo ? 0.3125f : 0.0625f) : 0.f;
        float cw0 = (x >= 2) ? (xo ? 0.0625f : 0.3125f) : 0.f;
        float cw2 = (x <= H - 3) ? (xo ? 0.3125f : 0.0625f) : 0.f;
        int r0 = max(h - 1, 0), r2 = min(h + 1, H2 - 1);
        int c0 = max(w - 1, 0), c2 = min(w + 1, H2 - 1);
        const float* R0 = gnc + (size_t)r0 * H2;
        const float* R1 = gnc + (size_t)h * H2;
        const float* R2 = gnc + (size_t)r2 * H2;
        float s0 = cw0 * R0[c0] + 0.625f * R0[w] + cw2 * R0[c2];
        float s1 = cw0 * R1[c0] + 0.625f * R1[w] + cw2 * R1[c2];
        float s2 = cw0 * R2[c0] + 0.625f * R2[w] + cw2 * R2[c2];
        val -= rw0 * s0 + 0.625f * s1 + rw2 * s2;
      }
      p[idx] = val;
      atomicAdd(&ls[c], val);
      atomicAdd(&ls[3 + c], val * val);
    }
  }
  __syncthreads();
  if (threadIdx.x < 6) atomicAdd(&st[threadIdx.x], ls[threadIdx.x]);
}

__global__ void prep_kernel(const float* __restrict__ rnd,
                            const float* __restrict__ st,   // st1[6], st2 at +6
                            float* __restrict__ B1, float* __restrict__ B2,
                            float* __restrict__ bias, float Np) {
  int j = blockIdx.x * 256 + threadIdx.x;
  if (j >= 512) return;
  float sum = 0.f, q = 0.f;
  for (int f = 0; f < 147; ++f) {
    float v = rnd[f * 512 + j];
    sum += v; q = fmaf(v, v, q);
  }
  float mean = sum * (1.f / 147.f);
  float var = (q - 147.f * mean * mean) * (1.f / 146.f);
  float inv1 = 1.f / sqrtf(var);
  float b1 = 0.f, b2 = 0.f;
#pragma unroll
  for (int c = 0; c < 3; ++c) {
    float m1 = st[c] / Np;
    float v1 = (st[3 + c] - Np * m1 * m1) / (Np - 1.f);
    float i1 = 1.f / (sqrtf(fmaxf(v1, 0.f)) + 1e-8f);
    float m2 = st[6 + c] / Np;
    float v2 = (st[9 + c] - Np * m2 * m2) / (Np - 1.f);
    float i2 = 1.f / (sqrtf(fmaxf(v2, 0.f)) + 1e-8f);
    for (int ff = 0; ff < 49; ++ff) {
      int f = c * 49 + ff;
      float rv = rnd[f * 512 + j] * inv1;
      float w1 = rv * i1; B1[f * 512 + j] = w1; b1 = fmaf(m1, w1, b1);
      float w2 = rv * i2; B2[f * 512 + j] = w2; b2 = fmaf(m2, w2, b2);
    }
  }
  for (int f = 147; f < 160; ++f) { B1[f * 512 + j] = 0.f; B2[f * 512 + j] = 0.f; }
  bias[j] = b1; bias[512 + j] = b2;
}

// C[n][m] col-major (stride 16384) = A[M][160] * B[160][512] - bias[n]
#define GBM 128
#define GBN 128
#define GBK 16
__global__ __launch_bounds__(256) void gemm_kernel(
    const float* __restrict__ A, const float* __restrict__ B,
    const float* __restrict__ bias, float* __restrict__ C, int M) {
  __shared__ __align__(16) float As[GBK][GBM + 4];
  __shared__ __align__(16) float Bs[GBK][GBN];
  int bm = blockIdx.x * GBM;
  int bn = blockIdx.y * GBN;
  int tid = threadIdx.x;
  int tm = tid & 15;
  int tn = tid >> 4;
  float acc[8][8] = {{0.f}};
  for (int k0 = 0; k0 < 160; k0 += GBK) {
#pragma unroll
    for (int i = 0; i < 2; ++i) {
      int q = tid + i * 256;
      int r = q >> 2, c4 = (q & 3) << 2;
      float4 va = *(const float4*)(A + (size_t)(bm + r) * 160 + k0 + c4);
      As[c4 + 0][r] = va.x; As[c4 + 1][r] = va.y;
      As[c4 + 2][r] = va.z; As[c4 + 3][r] = va.w;
    }
#pragma unroll
    for (int i = 0; i < 2; ++i) {
      int q = tid + i * 256;
      int r = q >> 5, c = (q & 31) << 2;
      *(float4*)(&Bs[r][c]) = *(const float4*)(B + (size_t)(k0 + r) * 512 + bn + c);
    }
    __syncthreads();
#pragma unroll
    for (int kk = 0; kk < GBK; ++kk) {
      float4 a0 = *(const float4*)(&As[kk][tm * 8]);
      float4 a1 = *(const float4*)(&As[kk][tm * 8 + 4]);
      float4 b0 = *(const float4*)(&Bs[kk][tn * 8]);
      float4 b1 = *(const float4*)(&Bs[kk][tn * 8 + 4]);
      float av[8] = {a0.x, a0.y, a0.z, a0.w, a1.x, a1.y, a1.z, a1.w};
      float bv[8] = {b0.x, b0.y, b0.z, b0.w, b1.x, b1.y, b1.z, b1.w};
#pragma unroll
      for (int i = 0; i < 8; ++i)
#pragma unroll
        for (int jj = 0; jj < 8; ++jj)
          acc[i][jj] = fmaf(av[i], bv[jj], acc[i][jj]);
    }
    __syncthreads();
  }
#pragma unroll
  for (int jj = 0; jj < 8; ++jj) {
    int n = bn + tn * 8 + jj;
    float bb = bias[n];
    float4 v0 = make_float4(acc[0][jj] - bb, acc[1][jj] - bb, acc[2][jj] - bb, acc[3][jj] - bb);
    float4 v1 = make_float4(acc[4][jj] - bb, acc[5][jj] - bb, acc[6][jj] - bb, acc[7][jj] - bb);
    float* cp = C + (size_t)n * 16384 + bm + tm * 8;
    *(float4*)cp = v0;
    *(float4*)(cp + 4) = v1;
  }
}

// ---- hybrid sort + diff ----
// co-rank: smallest i in [max(0,so-L), min(so,L)] s.t. merged prefix of size
// so takes i from A, so-i from B. Convention: advance while A[i] < B[so-1-i].
__device__ inline int corank(const float* __restrict__ s, int pb, int L, int so) {
  int lo = so - L; lo = lo < 0 ? 0 : lo;
  int hi = so < L ? so : L;
  while (lo < hi) {
    int mid = (lo + hi) >> 1;
    float a = s[pb + mid];
    float b = s[pb + L + so - 1 - mid];
    if (a < b) lo = mid + 1; else hi = mid;
  }
  return lo;
}

// 4 merge-path rounds over a 16384-float LDS buffer; v holds this thread's 16
// wave-sorted values on entry (already staged into s), and its 16 final-merged
// values (positions bi..bi+15) on exit. Exits with all threads synced.
__device__ __forceinline__ void merge4(float (&v)[16], float* __restrict__ s,
                                       int t, int bi) {
#pragma unroll
  for (int L = 1024; L <= 8192; L <<= 1) {
    int pb = bi & ~(2 * L - 1);
    int so = bi - pb;
    int i0 = corank(s, pb, L, so);
    int nxt = __shfl_down(i0, 1, 64);   // lane t+1's i0 == our i1
    int i1;
    if (((so + 16) & (2 * L - 1)) == 0) i1 = L;          // last window in partition
    else if ((t & 63) == 63) i1 = corank(s, pb, L, so + 16);  // wave boundary
    else i1 = nxt;
    int na = i1 - i0;
    int j1 = so + 16 - i1;
#pragma unroll
    for (int q = 0; q < 16; ++q) {
      int idx = (q < na) ? (pb + i0 + q)
                         : (pb + L + j1 - 1 - (q - na));
      v[q] = s[idx];
    }
    // window = ascending A-part then descending B-part => bitonic; merge up
#pragma unroll
    for (int j = 8; j >= 1; j >>= 1) {
#pragma unroll
      for (int q = 0; q < 16; ++q) {
        if ((q & j) == 0) {
          float a = v[q], b = v[q | j];
          v[q] = fminf(a, b);
          v[q | j] = fmaxf(a, b);
        }
      }
    }
    __syncthreads();
    if (L < 8192) {
#pragma unroll
      for (int i = 0; i < 4; ++i)
        *(float4*)(&s[bi + i * 4]) =
            make_float4(v[i * 4], v[i * 4 + 1], v[i * 4 + 2], v[i * 4 + 3]);
      __syncthreads();
    }
  }
}

__global__ __launch_bounds__(1024, 8) void sortdiff_kernel(
    const float* __restrict__ proj1, const float* __restrict__ proj2,
    float* __restrict__ sum, int m) {
  __shared__ float s[16384];
  int t = threadIdx.x;
  int col = blockIdx.x;  // 0..511
  const float INF = __builtin_huge_valf();
  float va[16], vb[16];
  int bi = t << 4;

  const float* pa = proj1 + (size_t)col * 16384;
  const float* pbp = proj2 + (size_t)col * 16384;
  if (bi < m) {
#pragma unroll
    for (int i = 0; i < 4; ++i) {
      float4 A4 = *(const float4*)(pa + bi + i * 4);
      va[i * 4 + 0] = A4.x; va[i * 4 + 1] = A4.y;
      va[i * 4 + 2] = A4.z; va[i * 4 + 3] = A4.w;
      float4 B4 = *(const float4*)(pbp + bi + i * 4);
      vb[i * 4 + 0] = B4.x; vb[i * 4 + 1] = B4.y;
      vb[i * 4 + 2] = B4.z; vb[i * 4 + 3] = B4.w;
    }
  } else {
#pragma unroll
    for (int r = 0; r < 16; ++r) { va[r] = INF; vb[r] = INF; }
  }

  // ---- in-thread bitonic, k=2..8, both columns interleaved (2x ILP)
#pragma unroll
  for (int k = 2; k <= 8; k <<= 1) {
#pragma unroll
    for (int j = k >> 1; j >= 1; j >>= 1) {
#pragma unroll
      for (int r = 0; r < 16; ++r) {
        if ((r & j) == 0) {
          bool up = ((r & k) == 0);
          float a0 = va[r], b0 = va[r | j];
          float lo0 = fminf(a0, b0), hi0 = fmaxf(a0, b0);
          va[r] = up ? lo0 : hi0;
          va[r | j] = up ? hi0 : lo0;
          float a1 = vb[r], b1 = vb[r | j];
          float lo1 = fminf(a1, b1), hi1 = fmaxf(a1, b1);
          vb[r] = up ? lo1 : hi1;
          vb[r | j] = up ? hi1 : lo1;
        }
      }
    }
  }
  // ---- wave-level bitonic, k=16..1024 (k=1024 forced ascending), interleaved
  for (int k = 16; k <= 1024; k <<= 1) {
    bool upk = (k == 1024) || ((bi & k) == 0);
    for (int j = k >> 1; j >= 16; j >>= 1) {
      int d = j >> 4;  // lanes 1..32
      bool keepmin = (upk == ((t & d) == 0));
#pragma unroll
      for (int r = 0; r < 16; ++r) {
        float qa = __shfl_xor(va[r], d, 64);
        float qb = __shfl_xor(vb[r], d, 64);
        float loa = fminf(va[r], qa), hia = fmaxf(va[r], qa);
        va[r] = keepmin ? loa : hia;
        float lob = fminf(vb[r], qb), hib = fmaxf(vb[r], qb);
        vb[r] = keepmin ? lob : hib;
      }
    }
#pragma unroll
    for (int j = 8; j >= 1; j >>= 1) {
#pragma unroll
      for (int r = 0; r < 16; ++r) {
        if ((r & j) == 0) {
          float a0 = va[r], b0 = va[r | j];
          float lo0 = fminf(a0, b0), hi0 = fmaxf(a0, b0);
          va[r] = upk ? lo0 : hi0;
          va[r | j] = upk ? hi0 : lo0;
          float a1 = vb[r], b1 = vb[r | j];
          float lo1 = fminf(a1, b1), hi1 = fmaxf(a1, b1);
          vb[r] = upk ? lo1 : hi1;
          vb[r | j] = upk ? hi1 : lo1;
        }
      }
    }
  }

  // each wave's 1024 elements of A and B now sorted ascending.
  // column A: stage to LDS, 4 merge rounds; result stays in va.
#pragma unroll
  for (int i = 0; i < 4; ++i)
    *(float4*)(&s[bi + i * 4]) =
        make_float4(va[i * 4], va[i * 4 + 1], va[i * 4 + 2], va[i * 4 + 3]);
  __syncthreads();
  merge4(va, s, t, bi);

  // column B: reuse LDS (merge4 exits synced); result lands in vb.
#pragma unroll
  for (int i = 0; i < 4; ++i)
    *(float4*)(&s[bi + i * 4]) =
        make_float4(vb[i * 4], vb[i * 4 + 1], vb[i * 4 + 2], vb[i * 4 + 3]);
  __syncthreads();
  merge4(vb, s, t, bi);

  float acc = 0.f;
  if (bi < m) {
#pragma unroll
    for (int q = 0; q < 16; ++q) acc += fabsf(va[q] - vb[q]);
  }

#pragma unroll
  for (int o = 32; o > 0; o >>= 1) acc += __shfl_down(acc, o, 64);
  if ((t & 63) == 0) s[t >> 6] = acc;
  __syncthreads();
  if (t == 0) {
    float tot = 0.f;
    for (int i = 0; i < 16; ++i) tot += s[i];
    atomicAdd(sum, tot);
  }
}

__global__ void final_kernel(const float* __restrict__ sums, float* __restrict__ out) {
  float r = sums[0] * (1.f / 8388608.f) + sums[1] * (1.f / 8388608.f) +
            sums[2] * (1.f / 8388608.f) + sums[3] * (1.f / 8388608.f) +
            sums[4] * (1.f / 6553600.f);
  out[0] = r * (1000.f / 5.f);
}

// ---------------------------------------------------------------------------

extern "C" void kernel_launch(void* const* d_in, const int* in_sizes, int n_in,
                              void* d_out, int out_size, void* d_ws, size_t ws_size,
                              hipStream_t stream) {
  const float* xin = (const float*)d_in[0];
  const float* yin = (const float*)d_in[1];
  float* out = (float*)d_out;

  char* base = (char*)d_ws;
  size_t off = 0;
  auto alloc = [&](size_t nfloats) -> float* {
    float* p = (float*)(base + off);
    off += ((nfloats * 4) + 255) & ~(size_t)255;
    return p;
  };
  float* gX[5];
  float* gY[5];
  gX[0] = (float*)xin;
  gY[0] = (float*)yin;
  gX[1] = alloc(6291456); gX[2] = alloc(1572864); gX[3] = alloc(393216); gX[4] = alloc(98304);
  gY[1] = alloc(6291456); gY[2] = alloc(1572864); gY[3] = alloc(393216); gY[4] = alloc(98304);
  float* p1 = alloc((size_t)16384 * 160);
  float* p2 = alloc((size_t)16384 * 160);
  float* rnd = alloc(160 * 512);
  float* B1 = alloc(160 * 512);
  float* B2 = alloc(160 * 512);
  float* biasb = alloc(1024);
  float* proj1 = alloc((size_t)16384 * 512);
  float* proj2 = alloc((size_t)16384 * 512);
  float* misc = alloc(128);

  static const int Hs[5] = {256, 128, 64, 32, 16};

  init_kernel<<<1, 128, 0, stream>>>(misc);
  for (int t = 0; t < 2; ++t) {
    const float* in0 = t ? yin : xin;
    float** g = t ? gY : gX;
    down_kernel<<<(384 * 128 * 128 + 255) / 256, 256, 0, stream>>>(in0, g[1], 256, 256, 384 * 128 * 128);
    down_kernel<<<(384 * 64 * 64 + 255) / 256, 256, 0, stream>>>(g[1], g[2], 128, 128, 384 * 64 * 64);
    down_kernel<<<(384 * 32 * 32 + 255) / 256, 256, 0, stream>>>(g[2], g[3], 64, 64, 384 * 32 * 32);
    down_kernel<<<(384 * 16 * 16 + 255) / 256, 256, 0, stream>>>(g[3], g[4], 32, 32, 384 * 16 * 16);
  }
  for (int l = 0; l < 5; ++l) {
    int H = Hs[l];
    int Wm6 = H - 6;
    int n = Wm6 * Wm6;
    int nd = n < 128 ? n : 128;
    int M = 128 * nd;
    randgen_kernel<<<320, 256, 0, stream>>>(rnd, g_tbl.kp0[l], g_tbl.kp1[l]);
    int totalE = M * 160;
    float* st1 = misc + 8 + l * 16;
    float* st2 = st1 + 6;
    extract_kernel<<<(totalE + 255) / 256, 256, 0, stream>>>(
        gX[l], (l < 4) ? gX[l + 1] : nullptr, p1, st1, g_tbl.rcs[l], H, nd, (l < 4) ? 1 : 0, totalE);
    extract_kernel<<<(totalE + 255) / 256, 256, 0, stream>>>(
        gY[l], (l < 4) ? gY[l + 1] : nullptr, p2, st2, g_tbl.rcs[l], H, nd, (l < 4) ? 1 : 0, totalE);
    prep_kernel<<<2, 256, 0, stream>>>(rnd, st1, B1, B2, biasb, (float)M * 49.f);
    dim3 gg(M / 128, 4);
    gemm_kernel<<<gg, 256, 0, stream>>>(p1, B1, biasb, proj1, M);
    gemm_kernel<<<gg, 256, 0, stream>>>(p2, B2, biasb + 512, proj2, M);
    sortdiff_kernel<<<512, 1024, 0, stream>>>(proj1, proj2, misc + l, M);
  }
  final_kernel<<<1, 1, 0, stream>>>(misc, out);
}

// Round 2
// 2951.175 us; speedup vs baseline: 1.0662x; 1.0005x over previous
//
#include <hip/hip_runtime.h>
#include <hip/hip_bf16.h>
#include <cstdint>
#include <cmath>
#include <vector>
#include <algorithm>
#include <numeric>

// ---------------------------------------------------------------------------
// LapSWD loss. RNG = exact JAX partitionable threefry (verified absmax 0.0).
// R7: sortdiff rewritten as full merge-path mergesort (O(n log n)) replacing
// the O(n log^2 n) shuffle-bitonic:
//  - in-thread bitonic-16 network (80 CE, both columns interleaved for ILP),
//  - 10 merge-path rounds L=16..8192 through LDS. Rounds with L<=512 stay
//    inside one wave's 1024-element segment -> NO block barrier (wave64
//    lockstep + in-order DS pipe), only L>=1024 uses __syncthreads.
//  - neighbor-lane i1 co-rank via shfl_down kept from R6.
// Cuts per-thread CE count ~2.3x (12.5k -> 5.5k VALU); VALU-issue was 70%
// of the 168us kernel.
// ---------------------------------------------------------------------------

__constant__ float KW[5] = {0.0625f, 0.25f, 0.375f, 0.25f, 0.0625f};

struct RC { unsigned int rc[128]; };

// ---- threefry2x32 block cipher, exact JAX/XLA schedule ----
__host__ __device__ inline void tf2x32(uint32_t k0, uint32_t k1,
                                       uint32_t x0, uint32_t x1,
                                       uint32_t& o0, uint32_t& o1) {
  uint32_t k2 = k0 ^ k1 ^ 0x1BD11BDAu;
  x0 += k0; x1 += k1;
#define TFR(r) { x0 += x1; x1 = (x1 << r) | (x1 >> (32 - r)); x1 ^= x0; }
  TFR(13) TFR(15) TFR(26) TFR(6)   x0 += k1; x1 += k2 + 1u;
  TFR(17) TFR(29) TFR(16) TFR(24)  x0 += k2; x1 += k0 + 2u;
  TFR(13) TFR(15) TFR(26) TFR(6)   x0 += k0; x1 += k1 + 3u;
  TFR(17) TFR(29) TFR(16) TFR(24)  x0 += k1; x1 += k2 + 4u;
  TFR(13) TFR(15) TFR(26) TFR(6)   x0 += k2; x1 += k0 + 5u;
#undef TFR
  o0 = x0; o1 = x1;
}

// ---- host tables (pure constants; computed once at library load) ----
struct HostTables {
  RC rcs[5];
  uint32_t kp0[5], kp1[5];
  HostTables() {
    static const int Hs[5] = {256, 128, 64, 32, 16};
    for (int l = 0; l < 5; ++l) {
      uint32_t f0, f1;
      tf2x32(0u, 42u, 0u, (uint32_t)l, f0, f1);  // fold_in(key(42), l)
      uint32_t ik0, ik1;
      tf2x32(f0, f1, 0u, 0u, ik0, ik1);          // k_idx = split[0]
      tf2x32(f0, f1, 0u, 1u, kp0[l], kp1[l]);    // k_proj = split[1]
      int Wm6 = Hs[l] - 6;
      int n = Wm6 * Wm6;
      int nd = n < 128 ? n : 128;
      std::vector<int> perm(n);
      std::iota(perm.begin(), perm.end(), 0);
      int rounds = (int)std::ceil(3.0 * std::log((double)n) / std::log(4294967295.0));
      uint32_t key0 = ik0, key1 = ik1;
      std::vector<uint32_t> bits(n);
      std::vector<int> ord(n), tmp(n);
      for (int r = 0; r < rounds; ++r) {
        uint32_t nk0, nk1, s0, s1;
        tf2x32(key0, key1, 0u, 0u, nk0, nk1);
        tf2x32(key0, key1, 0u, 1u, s0, s1);
        key0 = nk0; key1 = nk1;
        for (int tt = 0; tt < n; ++tt) {
          uint32_t o0, o1;
          tf2x32(s0, s1, 0u, (uint32_t)tt, o0, o1);
          bits[tt] = o0 ^ o1;
        }
        std::iota(ord.begin(), ord.end(), 0);
        std::stable_sort(ord.begin(), ord.end(),
                         [&](int A, int B) { return bits[A] < bits[B]; });
        for (int i2 = 0; i2 < n; ++i2) tmp[i2] = perm[ord[i2]];
        perm.swap(tmp);
      }
      for (int d = 0; d < 128; ++d) {
        int vv = (d < nd) ? perm[d] : 0;
        rcs[l].rc[d] = ((uint32_t)(vv / Wm6) << 16) | (uint32_t)(vv % Wm6);
      }
    }
  }
};
static const HostTables g_tbl;

__device__ inline float erfinv_f(float x) {
  float w = -log1pf(-x * x);
  float p;
  if (w < 5.0f) {
    w = w - 2.5f;
    p = 2.81022636e-08f;
    p = fmaf(p, w, 3.43273939e-07f);
    p = fmaf(p, w, -3.5233877e-06f);
    p = fmaf(p, w, -4.39150654e-06f);
    p = fmaf(p, w, 0.00021858087f);
    p = fmaf(p, w, -0.00125372503f);
    p = fmaf(p, w, -0.00417768164f);
    p = fmaf(p, w, 0.246640727f);
    p = fmaf(p, w, 1.50140941f);
  } else {
    w = sqrtf(w) - 3.0f;
    p = -0.000200214257f;
    p = fmaf(p, w, 0.000100950558f);
    p = fmaf(p, w, 0.00134934322f);
    p = fmaf(p, w, -0.00367342844f);
    p = fmaf(p, w, 0.00573950773f);
    p = fmaf(p, w, -0.0076224613f);
    p = fmaf(p, w, 0.00943887047f);
    p = fmaf(p, w, 1.00167406f);
    p = fmaf(p, w, 2.83297682f);
  }
  return p * x;
}

__device__ inline float bits_to_normal(uint32_t b) {
  union { uint32_t u; float f; } cv;
  cv.u = (b >> 9) | 0x3f800000u;
  float f = cv.f - 1.0f;
  const float lo = -0.99999994f;
  const float span = 1.0f - lo;
  float u = fmaxf(lo, __fadd_rn(__fmul_rn(f, span), lo));
  return 1.41421356237f * erfinv_f(u);
}

// ---- kernels ----

__global__ void init_kernel(float* m) {
  int i = threadIdx.x;
  if (i < 128) m[i] = 0.f;
}

__global__ __launch_bounds__(256) void down_kernel(
    const float* __restrict__ in, float* __restrict__ out,
    int H, int W, int total) {
  int idx = blockIdx.x * 256 + threadIdx.x;
  if (idx >= total) return;
  int Wo = W >> 1, Ho = H >> 1;
  int ox = idx % Wo;
  int t = idx / Wo;
  int oy = t % Ho;
  int bc = t / Ho;
  const float* src = in + (size_t)bc * H * W;
  float s = 0.f;
#pragma unroll
  for (int u = 0; u < 5; ++u) {
    int y = 2 * oy + u - 2;
    if (y < 0 || y >= H) continue;
    const float* r = src + (size_t)y * W;
#pragma unroll
    for (int v = 0; v < 5; ++v) {
      int x = 2 * ox + v - 2;
      if (x < 0 || x >= W) continue;
      s += KW[u] * KW[v] * r[x];
    }
  }
  out[idx] = s;
}

__global__ void randgen_kernel(float* __restrict__ rnd, uint32_t k0, uint32_t k1) {
  int t = blockIdx.x * 256 + threadIdx.x;  // grid covers 81920
  const int total = 75264;                 // 147*512
  if (t < total) {
    uint32_t o0, o1;
    tf2x32(k0, k1, 0u, (uint32_t)t, o0, o1);
    rnd[t] = bits_to_normal(o0 ^ o1);
  }
}

// extract + per-channel stats (sum, sumsq) fused
__global__ __launch_bounds__(256) void extract_kernel(
    const float* __restrict__ g, const float* __restrict__ gn,
    float* __restrict__ p, float* __restrict__ st, RC rcs,
    int H, int nd, int useLap, int total) {
  __shared__ float ls[6];
  if (threadIdx.x < 6) ls[threadIdx.x] = 0.f;
  __syncthreads();
  int idx = blockIdx.x * 256 + threadIdx.x;
  if (idx < total) {                    // total = M*160
    int col = idx % 160;
    if (col < 147) {
      int row = idx / 160;
      int d = row % nd, b = row / nd;
      int c = col / 49, uv = col % 49, u = uv / 7, v = uv % 7;
      unsigned rc = rcs.rc[d];
      int y = (int)(rc >> 16) + u;
      int x = (int)(rc & 0xffffu) + v;
      const float* gc = g + ((size_t)(b * 3 + c)) * H * H;
      float val = gc[(size_t)y * H + x];
      if (useLap) {
        int H2 = H >> 1;
        const float* gnc = gn + ((size_t)(b * 3 + c)) * H2 * H2;
        int h = y >> 1, w = x >> 1;
        int yo = y & 1, xo = x & 1;
        float rw0 = (y >= 2) ? (yo ? 0.0625f : 0.3125f) : 0.f;
        float rw2 = (y <= H - 3) ? (yo ? 0.3125f : 0.0625f) : 0.f;
        float cw0 = (x >= 2) ? (xo ? 0.0625f : 0.3125f) : 0.f;
        float cw2 = (x <= H - 3) ? (xo ? 0.3125f : 0.0625f) : 0.f;
        int r0 = max(h - 1, 0), r2 = min(h + 1, H2 - 1);
        int c0 = max(w - 1, 0), c2 = min(w + 1, H2 - 1);
        const float* R0 = gnc + (size_t)r0 * H2;
        const float* R1 = gnc + (size_t)h * H2;
        const float* R2 = gnc + (size_t)r2 * H2;
        float s0 = cw0 * R0[c0] + 0.625f * R0[w] + cw2 * R0[c2];
        float s1 = cw0 * R1[c0] + 0.625f * R1[w] + cw2 * R1[c2];
        float s2 = cw0 * R2[c0] + 0.625f * R2[w] + cw2 * R2[c2];
        val -= rw0 * s0 + 0.625f * s1 + rw2 * s2;
      }
      p[idx] = val;
      atomicAdd(&ls[c], val);
      atomicAdd(&ls[3 + c], val * val);
    }
  }
  __syncthreads();
  if (threadIdx.x < 6) atomicAdd(&st[threadIdx.x], ls[threadIdx.x]);
}

__global__ void prep_kernel(const float* __restrict__ rnd,
                            const float* __restrict__ st,   // st1[6], st2 at +6
                            float* __restrict__ B1, float* __restrict__ B2,
                            float* __restrict__ bias, float Np) {
  int j = blockIdx.x * 256 + threadIdx.x;
  if (j >= 512) return;
  float sum = 0.f, q = 0.f;
  for (int f = 0; f < 147; ++f) {
    float v = rnd[f * 512 + j];
    sum += v; q = fmaf(v, v, q);
  }
  float mean = sum * (1.f / 147.f);
  float var = (q - 147.f * mean * mean) * (1.f / 146.f);
  float inv1 = 1.f / sqrtf(var);
  float b1 = 0.f, b2 = 0.f;
#pragma unroll
  for (int c = 0; c < 3; ++c) {
    float m1 = st[c] / Np;
    float v1 = (st[3 + c] - Np * m1 * m1) / (Np - 1.f);
    float i1 = 1.f / (sqrtf(fmaxf(v1, 0.f)) + 1e-8f);
    float m2 = st[6 + c] / Np;
    float v2 = (st[9 + c] - Np * m2 * m2) / (Np - 1.f);
    float i2 = 1.f / (sqrtf(fmaxf(v2, 0.f)) + 1e-8f);
    for (int ff = 0; ff < 49; ++ff) {
      int f = c * 49 + ff;
      float rv = rnd[f * 512 + j] * inv1;
      float w1 = rv * i1; B1[f * 512 + j] = w1; b1 = fmaf(m1, w1, b1);
      float w2 = rv * i2; B2[f * 512 + j] = w2; b2 = fmaf(m2, w2, b2);
    }
  }
  for (int f = 147; f < 160; ++f) { B1[f * 512 + j] = 0.f; B2[f * 512 + j] = 0.f; }
  bias[j] = b1; bias[512 + j] = b2;
}

// C[n][m] col-major (stride 16384) = A[M][160] * B[160][512] - bias[n]
#define GBM 128
#define GBN 128
#define GBK 16
__global__ __launch_bounds__(256) void gemm_kernel(
    const float* __restrict__ A, const float* __restrict__ B,
    const float* __restrict__ bias, float* __restrict__ C, int M) {
  __shared__ __align__(16) float As[GBK][GBM + 4];
  __shared__ __align__(16) float Bs[GBK][GBN];
  int bm = blockIdx.x * GBM;
  int bn = blockIdx.y * GBN;
  int tid = threadIdx.x;
  int tm = tid & 15;
  int tn = tid >> 4;
  float acc[8][8] = {{0.f}};
  for (int k0 = 0; k0 < 160; k0 += GBK) {
#pragma unroll
    for (int i = 0; i < 2; ++i) {
      int q = tid + i * 256;
      int r = q >> 2, c4 = (q & 3) << 2;
      float4 va = *(const float4*)(A + (size_t)(bm + r) * 160 + k0 + c4);
      As[c4 + 0][r] = va.x; As[c4 + 1][r] = va.y;
      As[c4 + 2][r] = va.z; As[c4 + 3][r] = va.w;
    }
#pragma unroll
    for (int i = 0; i < 2; ++i) {
      int q = tid + i * 256;
      int r = q >> 5, c = (q & 31) << 2;
      *(float4*)(&Bs[r][c]) = *(const float4*)(B + (size_t)(k0 + r) * 512 + bn + c);
    }
    __syncthreads();
#pragma unroll
    for (int kk = 0; kk < GBK; ++kk) {
      float4 a0 = *(const float4*)(&As[kk][tm * 8]);
      float4 a1 = *(const float4*)(&As[kk][tm * 8 + 4]);
      float4 b0 = *(const float4*)(&Bs[kk][tn * 8]);
      float4 b1 = *(const float4*)(&Bs[kk][tn * 8 + 4]);
      float av[8] = {a0.x, a0.y, a0.z, a0.w, a1.x, a1.y, a1.z, a1.w};
      float bv[8] = {b0.x, b0.y, b0.z, b0.w, b1.x, b1.y, b1.z, b1.w};
#pragma unroll
      for (int i = 0; i < 8; ++i)
#pragma unroll
        for (int jj = 0; jj < 8; ++jj)
          acc[i][jj] = fmaf(av[i], bv[jj], acc[i][jj]);
    }
    __syncthreads();
  }
#pragma unroll
  for (int jj = 0; jj < 8; ++jj) {
    int n = bn + tn * 8 + jj;
    float bb = bias[n];
    float4 v0 = make_float4(acc[0][jj] - bb, acc[1][jj] - bb, acc[2][jj] - bb, acc[3][jj] - bb);
    float4 v1 = make_float4(acc[4][jj] - bb, acc[5][jj] - bb, acc[6][jj] - bb, acc[7][jj] - bb);
    float* cp = C + (size_t)n * 16384 + bm + tm * 8;
    *(float4*)cp = v0;
    *(float4*)(cp + 4) = v1;
  }
}

// ---- merge-path sort + diff ----
// co-rank: smallest i in [max(0,so-L), min(so,L)] s.t. merged prefix of size
// so takes i from A, so-i from B. Convention: advance while A[i] < B[so-1-i].
__device__ inline int corank(const float* __restrict__ s, int pb, int L, int so) {
  int lo = so - L; lo = lo < 0 ? 0 : lo;
  int hi = so < L ? so : L;
  while (lo < hi) {
    int mid = (lo + hi) >> 1;
    float a = s[pb + mid];
    float b = s[pb + L + so - 1 - mid];
    if (a < b) lo = mid + 1; else hi = mid;
  }
  return lo;
}

// One merge-path round: v holds this thread's 16 values of a sorted run of
// length L; after the call v holds its 16 values of the merged 2L run.
// crosswave=false (L<=512): window 2L fits in this wave's 1024-elem segment,
// no block barrier needed (wave64 lockstep + in-order DS pipe).
// crosswave=true: write;sync;read;sync.
__device__ __forceinline__ void merge_round(float (&v)[16], float* __restrict__ s,
                                            int t, int bi, int L, bool crosswave) {
  *(float4*)(&s[bi])      = make_float4(v[0], v[1], v[2], v[3]);
  *(float4*)(&s[bi + 4])  = make_float4(v[4], v[5], v[6], v[7]);
  *(float4*)(&s[bi + 8])  = make_float4(v[8], v[9], v[10], v[11]);
  *(float4*)(&s[bi + 12]) = make_float4(v[12], v[13], v[14], v[15]);
  if (crosswave) __syncthreads();
  else __builtin_amdgcn_wave_barrier();
  int pb = bi & ~(2 * L - 1);
  int so = bi - pb;
  int i0 = corank(s, pb, L, so);
  int nxt = __shfl_down(i0, 1, 64);   // lane t+1's i0 == our i1
  int i1;
  if (((so + 16) & (2 * L - 1)) == 0) i1 = L;              // last window slot
  else if (crosswave && (t & 63) == 63) i1 = corank(s, pb, L, so + 16);
  else i1 = nxt;
  int na = i1 - i0;
  int j1 = so + 16 - i1;
#pragma unroll
  for (int q = 0; q < 16; ++q) {
    int idx = (q < na) ? (pb + i0 + q)
                       : (pb + L + j1 - 1 - (q - na));
    v[q] = s[idx];
  }
  // window = ascending A-part then descending B-part => bitonic; merge up
#pragma unroll
  for (int j = 8; j >= 1; j >>= 1) {
#pragma unroll
    for (int q = 0; q < 16; ++q) {
      if ((q & j) == 0) {
        float a = v[q], b = v[q | j];
        v[q] = fminf(a, b);
        v[q | j] = fmaxf(a, b);
      }
    }
  }
  if (crosswave) __syncthreads();
}

// full 16384-element sort of one column (entry: v = 16 ascending-sorted
// values at positions bi..bi+15). Exits with all threads synced.
__device__ __forceinline__ void mergesort_col(float (&v)[16], float* __restrict__ s,
                                              int t, int bi) {
  for (int L = 16; L <= 512; L <<= 1) merge_round(v, s, t, bi, L, false);
  for (int L = 1024; L <= 8192; L <<= 1) merge_round(v, s, t, bi, L, true);
}

__global__ __launch_bounds__(1024, 8) void sortdiff_kernel(
    const float* __restrict__ proj1, const float* __restrict__ proj2,
    float* __restrict__ sum, int m) {
  __shared__ float s[16384];
  int t = threadIdx.x;
  int col = blockIdx.x;  // 0..511
  const float INF = __builtin_huge_valf();
  float va[16], vb[16];
  int bi = t << 4;

  const float* pa = proj1 + (size_t)col * 16384;
  const float* pbp = proj2 + (size_t)col * 16384;
  if (bi < m) {
#pragma unroll
    for (int i = 0; i < 4; ++i) {
      float4 A4 = *(const float4*)(pa + bi + i * 4);
      va[i * 4 + 0] = A4.x; va[i * 4 + 1] = A4.y;
      va[i * 4 + 2] = A4.z; va[i * 4 + 3] = A4.w;
      float4 B4 = *(const float4*)(pbp + bi + i * 4);
      vb[i * 4 + 0] = B4.x; vb[i * 4 + 1] = B4.y;
      vb[i * 4 + 2] = B4.z; vb[i * 4 + 3] = B4.w;
    }
  } else {
#pragma unroll
    for (int r = 0; r < 16; ++r) { va[r] = INF; vb[r] = INF; }
  }

  // ---- in-thread bitonic-16 sort, both columns interleaved (2x ILP)
#pragma unroll
  for (int k = 2; k <= 16; k <<= 1) {
#pragma unroll
    for (int j = k >> 1; j >= 1; j >>= 1) {
#pragma unroll
      for (int r = 0; r < 16; ++r) {
        if ((r & j) == 0) {
          bool up = ((r & k) == 0);   // k=16: always true for r<16
          float a0 = va[r], b0 = va[r | j];
          float lo0 = fminf(a0, b0), hi0 = fmaxf(a0, b0);
          va[r] = up ? lo0 : hi0;
          va[r | j] = up ? hi0 : lo0;
          float a1 = vb[r], b1 = vb[r | j];
          float lo1 = fminf(a1, b1), hi1 = fmaxf(a1, b1);
          vb[r] = up ? lo1 : hi1;
          vb[r | j] = up ? hi1 : lo1;
        }
      }
    }
  }

  // column A: 10 merge-path rounds; result stays in va. exits synced.
  mergesort_col(va, s, t, bi);
  // column B: reuse LDS; result lands in vb.
  mergesort_col(vb, s, t, bi);

  float acc = 0.f;
  if (bi < m) {
#pragma unroll
    for (int q = 0; q < 16; ++q) acc += fabsf(va[q] - vb[q]);
  }

#pragma unroll
  for (int o = 32; o > 0; o >>= 1) acc += __shfl_down(acc, o, 64);
  if ((t & 63) == 0) s[t >> 6] = acc;
  __syncthreads();
  if (t == 0) {
    float tot = 0.f;
    for (int i = 0; i < 16; ++i) tot += s[i];
    atomicAdd(sum, tot);
  }
}

__global__ void final_kernel(const float* __restrict__ sums, float* __restrict__ out) {
  float r = sums[0] * (1.f / 8388608.f) + sums[1] * (1.f / 8388608.f) +
            sums[2] * (1.f / 8388608.f) + sums[3] * (1.f / 8388608.f) +
            sums[4] * (1.f / 6553600.f);
  out[0] = r * (1000.f / 5.f);
}

// ---------------------------------------------------------------------------

extern "C" void kernel_launch(void* const* d_in, const int* in_sizes, int n_in,
                              void* d_out, int out_size, void* d_ws, size_t ws_size,
                              hipStream_t stream) {
  const float* xin = (const float*)d_in[0];
  const float* yin = (const float*)d_in[1];
  float* out = (float*)d_out;

  char* base = (char*)d_ws;
  size_t off = 0;
  auto alloc = [&](size_t nfloats) -> float* {
    float* p = (float*)(base + off);
    off += ((nfloats * 4) + 255) & ~(size_t)255;
    return p;
  };
  float* gX[5];
  float* gY[5];
  gX[0] = (float*)xin;
  gY[0] = (float*)yin;
  gX[1] = alloc(6291456); gX[2] = alloc(1572864); gX[3] = alloc(393216); gX[4] = alloc(98304);
  gY[1] = alloc(6291456); gY[2] = alloc(1572864); gY[3] = alloc(393216); gY[4] = alloc(98304);
  float* p1 = alloc((size_t)16384 * 160);
  float* p2 = alloc((size_t)16384 * 160);
  float* rnd = alloc(160 * 512);
  float* B1 = alloc(160 * 512);
  float* B2 = alloc(160 * 512);
  float* biasb = alloc(1024);
  float* proj1 = alloc((size_t)16384 * 512);
  float* proj2 = alloc((size_t)16384 * 512);
  float* misc = alloc(128);

  static const int Hs[5] = {256, 128, 64, 32, 16};

  init_kernel<<<1, 128, 0, stream>>>(misc);
  for (int t = 0; t < 2; ++t) {
    const float* in0 = t ? yin : xin;
    float** g = t ? gY : gX;
    down_kernel<<<(384 * 128 * 128 + 255) / 256, 256, 0, stream>>>(in0, g[1], 256, 256, 384 * 128 * 128);
    down_kernel<<<(384 * 64 * 64 + 255) / 256, 256, 0, stream>>>(g[1], g[2], 128, 128, 384 * 64 * 64);
    down_kernel<<<(384 * 32 * 32 + 255) / 256, 256, 0, stream>>>(g[2], g[3], 64, 64, 384 * 32 * 32);
    down_kernel<<<(384 * 16 * 16 + 255) / 256, 256, 0, stream>>>(g[3], g[4], 32, 32, 384 * 16 * 16);
  }
  for (int l = 0; l < 5; ++l) {
    int H = Hs[l];
    int Wm6 = H - 6;
    int n = Wm6 * Wm6;
    int nd = n < 128 ? n : 128;
    int M = 128 * nd;
    randgen_kernel<<<320, 256, 0, stream>>>(rnd, g_tbl.kp0[l], g_tbl.kp1[l]);
    int totalE = M * 160;
    float* st1 = misc + 8 + l * 16;
    float* st2 = st1 + 6;
    extract_kernel<<<(totalE + 255) / 256, 256, 0, stream>>>(
        gX[l], (l < 4) ? gX[l + 1] : nullptr, p1, st1, g_tbl.rcs[l], H, nd, (l < 4) ? 1 : 0, totalE);
    extract_kernel<<<(totalE + 255) / 256, 256, 0, stream>>>(
        gY[l], (l < 4) ? gY[l + 1] : nullptr, p2, st2, g_tbl.rcs[l], H, nd, (l < 4) ? 1 : 0, totalE);
    prep_kernel<<<2, 256, 0, stream>>>(rnd, st1, B1, B2, biasb, (float)M * 49.f);
    dim3 gg(M / 128, 4);
    gemm_kernel<<<gg, 256, 0, stream>>>(p1, B1, biasb, proj1, M);
    gemm_kernel<<<gg, 256, 0, stream>>>(p2, B2, biasb + 512, proj2, M);
    sortdiff_kernel<<<512, 1024, 0, stream>>>(proj1, proj2, misc + l, M);
  }
  final_kernel<<<1, 1, 0, stream>>>(misc, out);
}

// Round 3
// 2838.309 us; speedup vs baseline: 1.1086x; 1.0398x over previous
//
#include <hip/hip_runtime.h>
#include <hip/hip_bf16.h>
#include <cstdint>
#include <cmath>
#include <vector>
#include <algorithm>
#include <numeric>

// ---------------------------------------------------------------------------
// LapSWD loss. RNG = exact JAX partitionable threefry (verified absmax 0.0).
// R8: R7 merge-path mergesort + full 5-bit XOR bank swizzle on the LDS sort
// buffer: element i lives at s[i ^ ((i>>5)&31)].
//  - R7's scalar merge gathers had lanes at stride ~8 -> 16 lanes/bank
//    (SQ_LDS_BANK_CONFLICT 6.4e7 = ~100us of the 164us kernel). The row-XOR
//    spreads any power-of-2-strided lane pattern across all 32 banks.
//  - staging writes switch float4 -> 16 x b32 (XOR permutes low addr bits);
//    per-thread row is constant so writes stay a permuted contiguous block.
//  - corank binary-search reads swizzled identically.
// ---------------------------------------------------------------------------

#define SIDX(i) ((i) ^ (((i) >> 5) & 31))

__constant__ float KW[5] = {0.0625f, 0.25f, 0.375f, 0.25f, 0.0625f};

struct RC { unsigned int rc[128]; };

// ---- threefry2x32 block cipher, exact JAX/XLA schedule ----
__host__ __device__ inline void tf2x32(uint32_t k0, uint32_t k1,
                                       uint32_t x0, uint32_t x1,
                                       uint32_t& o0, uint32_t& o1) {
  uint32_t k2 = k0 ^ k1 ^ 0x1BD11BDAu;
  x0 += k0; x1 += k1;
#define TFR(r) { x0 += x1; x1 = (x1 << r) | (x1 >> (32 - r)); x1 ^= x0; }
  TFR(13) TFR(15) TFR(26) TFR(6)   x0 += k1; x1 += k2 + 1u;
  TFR(17) TFR(29) TFR(16) TFR(24)  x0 += k2; x1 += k0 + 2u;
  TFR(13) TFR(15) TFR(26) TFR(6)   x0 += k0; x1 += k1 + 3u;
  TFR(17) TFR(29) TFR(16) TFR(24)  x0 += k1; x1 += k2 + 4u;
  TFR(13) TFR(15) TFR(26) TFR(6)   x0 += k2; x1 += k0 + 5u;
#undef TFR
  o0 = x0; o1 = x1;
}

// ---- host tables (pure constants; computed once at library load) ----
struct HostTables {
  RC rcs[5];
  uint32_t kp0[5], kp1[5];
  HostTables() {
    static const int Hs[5] = {256, 128, 64, 32, 16};
    for (int l = 0; l < 5; ++l) {
      uint32_t f0, f1;
      tf2x32(0u, 42u, 0u, (uint32_t)l, f0, f1);  // fold_in(key(42), l)
      uint32_t ik0, ik1;
      tf2x32(f0, f1, 0u, 0u, ik0, ik1);          // k_idx = split[0]
      tf2x32(f0, f1, 0u, 1u, kp0[l], kp1[l]);    // k_proj = split[1]
      int Wm6 = Hs[l] - 6;
      int n = Wm6 * Wm6;
      int nd = n < 128 ? n : 128;
      std::vector<int> perm(n);
      std::iota(perm.begin(), perm.end(), 0);
      int rounds = (int)std::ceil(3.0 * std::log((double)n) / std::log(4294967295.0));
      uint32_t key0 = ik0, key1 = ik1;
      std::vector<uint32_t> bits(n);
      std::vector<int> ord(n), tmp(n);
      for (int r = 0; r < rounds; ++r) {
        uint32_t nk0, nk1, s0, s1;
        tf2x32(key0, key1, 0u, 0u, nk0, nk1);
        tf2x32(key0, key1, 0u, 1u, s0, s1);
        key0 = nk0; key1 = nk1;
        for (int tt = 0; tt < n; ++tt) {
          uint32_t o0, o1;
          tf2x32(s0, s1, 0u, (uint32_t)tt, o0, o1);
          bits[tt] = o0 ^ o1;
        }
        std::iota(ord.begin(), ord.end(), 0);
        std::stable_sort(ord.begin(), ord.end(),
                         [&](int A, int B) { return bits[A] < bits[B]; });
        for (int i2 = 0; i2 < n; ++i2) tmp[i2] = perm[ord[i2]];
        perm.swap(tmp);
      }
      for (int d = 0; d < 128; ++d) {
        int vv = (d < nd) ? perm[d] : 0;
        rcs[l].rc[d] = ((uint32_t)(vv / Wm6) << 16) | (uint32_t)(vv % Wm6);
      }
    }
  }
};
static const HostTables g_tbl;

__device__ inline float erfinv_f(float x) {
  float w = -log1pf(-x * x);
  float p;
  if (w < 5.0f) {
    w = w - 2.5f;
    p = 2.81022636e-08f;
    p = fmaf(p, w, 3.43273939e-07f);
    p = fmaf(p, w, -3.5233877e-06f);
    p = fmaf(p, w, -4.39150654e-06f);
    p = fmaf(p, w, 0.00021858087f);
    p = fmaf(p, w, -0.00125372503f);
    p = fmaf(p, w, -0.00417768164f);
    p = fmaf(p, w, 0.246640727f);
    p = fmaf(p, w, 1.50140941f);
  } else {
    w = sqrtf(w) - 3.0f;
    p = -0.000200214257f;
    p = fmaf(p, w, 0.000100950558f);
    p = fmaf(p, w, 0.00134934322f);
    p = fmaf(p, w, -0.00367342844f);
    p = fmaf(p, w, 0.00573950773f);
    p = fmaf(p, w, -0.0076224613f);
    p = fmaf(p, w, 0.00943887047f);
    p = fmaf(p, w, 1.00167406f);
    p = fmaf(p, w, 2.83297682f);
  }
  return p * x;
}

__device__ inline float bits_to_normal(uint32_t b) {
  union { uint32_t u; float f; } cv;
  cv.u = (b >> 9) | 0x3f800000u;
  float f = cv.f - 1.0f;
  const float lo = -0.99999994f;
  const float span = 1.0f - lo;
  float u = fmaxf(lo, __fadd_rn(__fmul_rn(f, span), lo));
  return 1.41421356237f * erfinv_f(u);
}

// ---- kernels ----

__global__ void init_kernel(float* m) {
  int i = threadIdx.x;
  if (i < 128) m[i] = 0.f;
}

__global__ __launch_bounds__(256) void down_kernel(
    const float* __restrict__ in, float* __restrict__ out,
    int H, int W, int total) {
  int idx = blockIdx.x * 256 + threadIdx.x;
  if (idx >= total) return;
  int Wo = W >> 1, Ho = H >> 1;
  int ox = idx % Wo;
  int t = idx / Wo;
  int oy = t % Ho;
  int bc = t / Ho;
  const float* src = in + (size_t)bc * H * W;
  float s = 0.f;
#pragma unroll
  for (int u = 0; u < 5; ++u) {
    int y = 2 * oy + u - 2;
    if (y < 0 || y >= H) continue;
    const float* r = src + (size_t)y * W;
#pragma unroll
    for (int v = 0; v < 5; ++v) {
      int x = 2 * ox + v - 2;
      if (x < 0 || x >= W) continue;
      s += KW[u] * KW[v] * r[x];
    }
  }
  out[idx] = s;
}

__global__ void randgen_kernel(float* __restrict__ rnd, uint32_t k0, uint32_t k1) {
  int t = blockIdx.x * 256 + threadIdx.x;  // grid covers 81920
  const int total = 75264;                 // 147*512
  if (t < total) {
    uint32_t o0, o1;
    tf2x32(k0, k1, 0u, (uint32_t)t, o0, o1);
    rnd[t] = bits_to_normal(o0 ^ o1);
  }
}

// extract + per-channel stats (sum, sumsq) fused
__global__ __launch_bounds__(256) void extract_kernel(
    const float* __restrict__ g, const float* __restrict__ gn,
    float* __restrict__ p, float* __restrict__ st, RC rcs,
    int H, int nd, int useLap, int total) {
  __shared__ float ls[6];
  if (threadIdx.x < 6) ls[threadIdx.x] = 0.f;
  __syncthreads();
  int idx = blockIdx.x * 256 + threadIdx.x;
  if (idx < total) {                    // total = M*160
    int col = idx % 160;
    if (col < 147) {
      int row = idx / 160;
      int d = row % nd, b = row / nd;
      int c = col / 49, uv = col % 49, u = uv / 7, v = uv % 7;
      unsigned rc = rcs.rc[d];
      int y = (int)(rc >> 16) + u;
      int x = (int)(rc & 0xffffu) + v;
      const float* gc = g + ((size_t)(b * 3 + c)) * H * H;
      float val = gc[(size_t)y * H + x];
      if (useLap) {
        int H2 = H >> 1;
        const float* gnc = gn + ((size_t)(b * 3 + c)) * H2 * H2;
        int h = y >> 1, w = x >> 1;
        int yo = y & 1, xo = x & 1;
        float rw0 = (y >= 2) ? (yo ? 0.0625f : 0.3125f) : 0.f;
        float rw2 = (y <= H - 3) ? (yo ? 0.3125f : 0.0625f) : 0.f;
        float cw0 = (x >= 2) ? (xo ? 0.0625f : 0.3125f) : 0.f;
        float cw2 = (x <= H - 3) ? (xo ? 0.3125f : 0.0625f) : 0.f;
        int r0 = max(h - 1, 0), r2 = min(h + 1, H2 - 1);
        int c0 = max(w - 1, 0), c2 = min(w + 1, H2 - 1);
        const float* R0 = gnc + (size_t)r0 * H2;
        const float* R1 = gnc + (size_t)h * H2;
        const float* R2 = gnc + (size_t)r2 * H2;
        float s0 = cw0 * R0[c0] + 0.625f * R0[w] + cw2 * R0[c2];
        float s1 = cw0 * R1[c0] + 0.625f * R1[w] + cw2 * R1[c2];
        float s2 = cw0 * R2[c0] + 0.625f * R2[w] + cw2 * R2[c2];
        val -= rw0 * s0 + 0.625f * s1 + rw2 * s2;
      }
      p[idx] = val;
      atomicAdd(&ls[c], val);
      atomicAdd(&ls[3 + c], val * val);
    }
  }
  __syncthreads();
  if (threadIdx.x < 6) atomicAdd(&st[threadIdx.x], ls[threadIdx.x]);
}

__global__ void prep_kernel(const float* __restrict__ rnd,
                            const float* __restrict__ st,   // st1[6], st2 at +6
                            float* __restrict__ B1, float* __restrict__ B2,
                            float* __restrict__ bias, float Np) {
  int j = blockIdx.x * 256 + threadIdx.x;
  if (j >= 512) return;
  float sum = 0.f, q = 0.f;
  for (int f = 0; f < 147; ++f) {
    float v = rnd[f * 512 + j];
    sum += v; q = fmaf(v, v, q);
  }
  float mean = sum * (1.f / 147.f);
  float var = (q - 147.f * mean * mean) * (1.f / 146.f);
  float inv1 = 1.f / sqrtf(var);
  float b1 = 0.f, b2 = 0.f;
#pragma unroll
  for (int c = 0; c < 3; ++c) {
    float m1 = st[c] / Np;
    float v1 = (st[3 + c] - Np * m1 * m1) / (Np - 1.f);
    float i1 = 1.f / (sqrtf(fmaxf(v1, 0.f)) + 1e-8f);
    float m2 = st[6 + c] / Np;
    float v2 = (st[9 + c] - Np * m2 * m2) / (Np - 1.f);
    float i2 = 1.f / (sqrtf(fmaxf(v2, 0.f)) + 1e-8f);
    for (int ff = 0; ff < 49; ++ff) {
      int f = c * 49 + ff;
      float rv = rnd[f * 512 + j] * inv1;
      float w1 = rv * i1; B1[f * 512 + j] = w1; b1 = fmaf(m1, w1, b1);
      float w2 = rv * i2; B2[f * 512 + j] = w2; b2 = fmaf(m2, w2, b2);
    }
  }
  for (int f = 147; f < 160; ++f) { B1[f * 512 + j] = 0.f; B2[f * 512 + j] = 0.f; }
  bias[j] = b1; bias[512 + j] = b2;
}

// C[n][m] col-major (stride 16384) = A[M][160] * B[160][512] - bias[n]
#define GBM 128
#define GBN 128
#define GBK 16
__global__ __launch_bounds__(256) void gemm_kernel(
    const float* __restrict__ A, const float* __restrict__ B,
    const float* __restrict__ bias, float* __restrict__ C, int M) {
  __shared__ __align__(16) float As[GBK][GBM + 4];
  __shared__ __align__(16) float Bs[GBK][GBN];
  int bm = blockIdx.x * GBM;
  int bn = blockIdx.y * GBN;
  int tid = threadIdx.x;
  int tm = tid & 15;
  int tn = tid >> 4;
  float acc[8][8] = {{0.f}};
  for (int k0 = 0; k0 < 160; k0 += GBK) {
#pragma unroll
    for (int i = 0; i < 2; ++i) {
      int q = tid + i * 256;
      int r = q >> 2, c4 = (q & 3) << 2;
      float4 va = *(const float4*)(A + (size_t)(bm + r) * 160 + k0 + c4);
      As[c4 + 0][r] = va.x; As[c4 + 1][r] = va.y;
      As[c4 + 2][r] = va.z; As[c4 + 3][r] = va.w;
    }
#pragma unroll
    for (int i = 0; i < 2; ++i) {
      int q = tid + i * 256;
      int r = q >> 5, c = (q & 31) << 2;
      *(float4*)(&Bs[r][c]) = *(const float4*)(B + (size_t)(k0 + r) * 512 + bn + c);
    }
    __syncthreads();
#pragma unroll
    for (int kk = 0; kk < GBK; ++kk) {
      float4 a0 = *(const float4*)(&As[kk][tm * 8]);
      float4 a1 = *(const float4*)(&As[kk][tm * 8 + 4]);
      float4 b0 = *(const float4*)(&Bs[kk][tn * 8]);
      float4 b1 = *(const float4*)(&Bs[kk][tn * 8 + 4]);
      float av[8] = {a0.x, a0.y, a0.z, a0.w, a1.x, a1.y, a1.z, a1.w};
      float bv[8] = {b0.x, b0.y, b0.z, b0.w, b1.x, b1.y, b1.z, b1.w};
#pragma unroll
      for (int i = 0; i < 8; ++i)
#pragma unroll
        for (int jj = 0; jj < 8; ++jj)
          acc[i][jj] = fmaf(av[i], bv[jj], acc[i][jj]);
    }
    __syncthreads();
  }
#pragma unroll
  for (int jj = 0; jj < 8; ++jj) {
    int n = bn + tn * 8 + jj;
    float bb = bias[n];
    float4 v0 = make_float4(acc[0][jj] - bb, acc[1][jj] - bb, acc[2][jj] - bb, acc[3][jj] - bb);
    float4 v1 = make_float4(acc[4][jj] - bb, acc[5][jj] - bb, acc[6][jj] - bb, acc[7][jj] - bb);
    float* cp = C + (size_t)n * 16384 + bm + tm * 8;
    *(float4*)cp = v0;
    *(float4*)(cp + 4) = v1;
  }
}

// ---- merge-path sort + diff (bank-swizzled LDS) ----
// co-rank: smallest i in [max(0,so-L), min(so,L)] s.t. merged prefix of size
// so takes i from A, so-i from B. Convention: advance while A[i] < B[so-1-i].
__device__ inline int corank(const float* __restrict__ s, int pb, int L, int so) {
  int lo = so - L; lo = lo < 0 ? 0 : lo;
  int hi = so < L ? so : L;
  while (lo < hi) {
    int mid = (lo + hi) >> 1;
    float a = s[SIDX(pb + mid)];
    float b = s[SIDX(pb + L + so - 1 - mid)];
    if (a < b) lo = mid + 1; else hi = mid;
  }
  return lo;
}

// One merge-path round: v holds this thread's 16 values of a sorted run of
// length L; after the call v holds its 16 values of the merged 2L run.
// crosswave=false (L<=512): window 2L fits in this wave's 1024-elem segment,
// no block barrier needed (wave64 lockstep + in-order DS pipe).
// crosswave=true: write;sync;read;sync.
__device__ __forceinline__ void merge_round(float (&v)[16], float* __restrict__ s,
                                            int t, int bi, int L, bool crosswave) {
  // staging: this thread's 16 elements share one 32-row -> constant XOR;
  // addresses are a permuted contiguous 16-block (conflict-free).
  int sw = (bi >> 5) & 31;
#pragma unroll
  for (int q = 0; q < 16; ++q) s[(bi + q) ^ sw] = v[q];
  if (crosswave) __syncthreads();
  else __builtin_amdgcn_wave_barrier();
  int pb = bi & ~(2 * L - 1);
  int so = bi - pb;
  int i0 = corank(s, pb, L, so);
  int nxt = __shfl_down(i0, 1, 64);   // lane t+1's i0 == our i1
  int i1;
  if (((so + 16) & (2 * L - 1)) == 0) i1 = L;              // last window slot
  else if (crosswave && (t & 63) == 63) i1 = corank(s, pb, L, so + 16);
  else i1 = nxt;
  int na = i1 - i0;
  int j1 = so + 16 - i1;
#pragma unroll
  for (int q = 0; q < 16; ++q) {
    int idx = (q < na) ? (pb + i0 + q)
                       : (pb + L + j1 - 1 - (q - na));
    v[q] = s[SIDX(idx)];
  }
  // window = ascending A-part then descending B-part => bitonic; merge up
#pragma unroll
  for (int j = 8; j >= 1; j >>= 1) {
#pragma unroll
    for (int q = 0; q < 16; ++q) {
      if ((q & j) == 0) {
        float a = v[q], b = v[q | j];
        v[q] = fminf(a, b);
        v[q | j] = fmaxf(a, b);
      }
    }
  }
  if (crosswave) __syncthreads();
}

// full 16384-element sort of one column (entry: v = 16 ascending-sorted
// values at positions bi..bi+15). Exits with all threads synced.
__device__ __forceinline__ void mergesort_col(float (&v)[16], float* __restrict__ s,
                                              int t, int bi) {
  for (int L = 16; L <= 512; L <<= 1) merge_round(v, s, t, bi, L, false);
  for (int L = 1024; L <= 8192; L <<= 1) merge_round(v, s, t, bi, L, true);
}

__global__ __launch_bounds__(1024, 8) void sortdiff_kernel(
    const float* __restrict__ proj1, const float* __restrict__ proj2,
    float* __restrict__ sum, int m) {
  __shared__ float s[16384];
  int t = threadIdx.x;
  int col = blockIdx.x;  // 0..511
  const float INF = __builtin_huge_valf();
  float va[16], vb[16];
  int bi = t << 4;

  const float* pa = proj1 + (size_t)col * 16384;
  const float* pbp = proj2 + (size_t)col * 16384;
  if (bi < m) {
#pragma unroll
    for (int i = 0; i < 4; ++i) {
      float4 A4 = *(const float4*)(pa + bi + i * 4);
      va[i * 4 + 0] = A4.x; va[i * 4 + 1] = A4.y;
      va[i * 4 + 2] = A4.z; va[i * 4 + 3] = A4.w;
      float4 B4 = *(const float4*)(pbp + bi + i * 4);
      vb[i * 4 + 0] = B4.x; vb[i * 4 + 1] = B4.y;
      vb[i * 4 + 2] = B4.z; vb[i * 4 + 3] = B4.w;
    }
  } else {
#pragma unroll
    for (int r = 0; r < 16; ++r) { va[r] = INF; vb[r] = INF; }
  }

  // ---- in-thread bitonic-16 sort, both columns interleaved (2x ILP)
#pragma unroll
  for (int k = 2; k <= 16; k <<= 1) {
#pragma unroll
    for (int j = k >> 1; j >= 1; j >>= 1) {
#pragma unroll
      for (int r = 0; r < 16; ++r) {
        if ((r & j) == 0) {
          bool up = ((r & k) == 0);   // k=16: always true for r<16
          float a0 = va[r], b0 = va[r | j];
          float lo0 = fminf(a0, b0), hi0 = fmaxf(a0, b0);
          va[r] = up ? lo0 : hi0;
          va[r | j] = up ? hi0 : lo0;
          float a1 = vb[r], b1 = vb[r | j];
          float lo1 = fminf(a1, b1), hi1 = fmaxf(a1, b1);
          vb[r] = up ? lo1 : hi1;
          vb[r | j] = up ? hi1 : lo1;
        }
      }
    }
  }

  // column A: 10 merge-path rounds; result stays in va. exits synced.
  mergesort_col(va, s, t, bi);
  // column B: reuse LDS; result lands in vb.
  mergesort_col(vb, s, t, bi);

  float acc = 0.f;
  if (bi < m) {
#pragma unroll
    for (int q = 0; q < 16; ++q) acc += fabsf(va[q] - vb[q]);
  }

#pragma unroll
  for (int o = 32; o > 0; o >>= 1) acc += __shfl_down(acc, o, 64);
  if ((t & 63) == 0) s[t >> 6] = acc;
  __syncthreads();
  if (t == 0) {
    float tot = 0.f;
    for (int i = 0; i < 16; ++i) tot += s[i];
    atomicAdd(sum, tot);
  }
}

__global__ void final_kernel(const float* __restrict__ sums, float* __restrict__ out) {
  float r = sums[0] * (1.f / 8388608.f) + sums[1] * (1.f / 8388608.f) +
            sums[2] * (1.f / 8388608.f) + sums[3] * (1.f / 8388608.f) +
            sums[4] * (1.f / 6553600.f);
  out[0] = r * (1000.f / 5.f);
}

// ---------------------------------------------------------------------------

extern "C" void kernel_launch(void* const* d_in, const int* in_sizes, int n_in,
                              void* d_out, int out_size, void* d_ws, size_t ws_size,
                              hipStream_t stream) {
  const float* xin = (const float*)d_in[0];
  const float* yin = (const float*)d_in[1];
  float* out = (float*)d_out;

  char* base = (char*)d_ws;
  size_t off = 0;
  auto alloc = [&](size_t nfloats) -> float* {
    float* p = (float*)(base + off);
    off += ((nfloats * 4) + 255) & ~(size_t)255;
    return p;
  };
  float* gX[5];
  float* gY[5];
  gX[0] = (float*)xin;
  gY[0] = (float*)yin;
  gX[1] = alloc(6291456); gX[2] = alloc(1572864); gX[3] = alloc(393216); gX[4] = alloc(98304);
  gY[1] = alloc(6291456); gY[2] = alloc(1572864); gY[3] = alloc(393216); gY[4] = alloc(98304);
  float* p1 = alloc((size_t)16384 * 160);
  float* p2 = alloc((size_t)16384 * 160);
  float* rnd = alloc(160 * 512);
  float* B1 = alloc(160 * 512);
  float* B2 = alloc(160 * 512);
  float* biasb = alloc(1024);
  float* proj1 = alloc((size_t)16384 * 512);
  float* proj2 = alloc((size_t)16384 * 512);
  float* misc = alloc(128);

  static const int Hs[5] = {256, 128, 64, 32, 16};

  init_kernel<<<1, 128, 0, stream>>>(misc);
  for (int t = 0; t < 2; ++t) {
    const float* in0 = t ? yin : xin;
    float** g = t ? gY : gX;
    down_kernel<<<(384 * 128 * 128 + 255) / 256, 256, 0, stream>>>(in0, g[1], 256, 256, 384 * 128 * 128);
    down_kernel<<<(384 * 64 * 64 + 255) / 256, 256, 0, stream>>>(g[1], g[2], 128, 128, 384 * 64 * 64);
    down_kernel<<<(384 * 32 * 32 + 255) / 256, 256, 0, stream>>>(g[2], g[3], 64, 64, 384 * 32 * 32);
    down_kernel<<<(384 * 16 * 16 + 255) / 256, 256, 0, stream>>>(g[3], g[4], 32, 32, 384 * 16 * 16);
  }
  for (int l = 0; l < 5; ++l) {
    int H = Hs[l];
    int Wm6 = H - 6;
    int n = Wm6 * Wm6;
    int nd = n < 128 ? n : 128;
    int M = 128 * nd;
    randgen_kernel<<<320, 256, 0, stream>>>(rnd, g_tbl.kp0[l], g_tbl.kp1[l]);
    int totalE = M * 160;
    float* st1 = misc + 8 + l * 16;
    float* st2 = st1 + 6;
    extract_kernel<<<(totalE + 255) / 256, 256, 0, stream>>>(
        gX[l], (l < 4) ? gX[l + 1] : nullptr, p1, st1, g_tbl.rcs[l], H, nd, (l < 4) ? 1 : 0, totalE);
    extract_kernel<<<(totalE + 255) / 256, 256, 0, stream>>>(
        gY[l], (l < 4) ? gY[l + 1] : nullptr, p2, st2, g_tbl.rcs[l], H, nd, (l < 4) ? 1 : 0, totalE);
    prep_kernel<<<2, 256, 0, stream>>>(rnd, st1, B1, B2, biasb, (float)M * 49.f);
    dim3 gg(M / 128, 4);
    gemm_kernel<<<gg, 256, 0, stream>>>(p1, B1, biasb, proj1, M);
    gemm_kernel<<<gg, 256, 0, stream>>>(p2, B2, biasb + 512, proj2, M);
    sortdiff_kernel<<<512, 1024, 0, stream>>>(proj1, proj2, misc + l, M);
  }
  final_kernel<<<1, 1, 0, stream>>>(misc, out);
}

// Round 5
// 2020.020 us; speedup vs baseline: 1.5577x; 1.4051x over previous
//
#include <hip/hip_runtime.h>
#include <hip/hip_bf16.h>
#include <cstdint>
#include <cmath>
#include <vector>
#include <algorithm>
#include <numeric>

// ---------------------------------------------------------------------------
// LapSWD loss. RNG = exact JAX partitionable threefry (verified absmax 0.0).
// R10 = R9 with the prep_kernel partial-reduction indexing bug fixed.
// R9 bug: (k=tid%12, r0=tid/12, stride 22) needs 264 threads but block has
// 256 -> rows r==21 (mod 22) never summed for k=4..11 -> absmax 15.
// Fix: k=tid>>4 (12 groups), r0=tid&15, stride 16: 192 threads, exact
// coverage (2048 % 16 == 0).
// R9: extract grid-stride at 2048 blocks, per-block partials, NO global
// atomics (kills the 138us atomic-convoy tail). Sort path: R7 merge-path
// mergesort + R8 XOR bank swizzle.
// ---------------------------------------------------------------------------

#define SIDX(i) ((i) ^ (((i) >> 5) & 31))
#define ENB 2048  // extract grid: 2048 blocks x 256 thr, grid-stride

__constant__ float KW[5] = {0.0625f, 0.25f, 0.375f, 0.25f, 0.0625f};

struct RC { unsigned int rc[128]; };

// ---- threefry2x32 block cipher, exact JAX/XLA schedule ----
__host__ __device__ inline void tf2x32(uint32_t k0, uint32_t k1,
                                       uint32_t x0, uint32_t x1,
                                       uint32_t& o0, uint32_t& o1) {
  uint32_t k2 = k0 ^ k1 ^ 0x1BD11BDAu;
  x0 += k0; x1 += k1;
#define TFR(r) { x0 += x1; x1 = (x1 << r) | (x1 >> (32 - r)); x1 ^= x0; }
  TFR(13) TFR(15) TFR(26) TFR(6)   x0 += k1; x1 += k2 + 1u;
  TFR(17) TFR(29) TFR(16) TFR(24)  x0 += k2; x1 += k0 + 2u;
  TFR(13) TFR(15) TFR(26) TFR(6)   x0 += k0; x1 += k1 + 3u;
  TFR(17) TFR(29) TFR(16) TFR(24)  x0 += k1; x1 += k2 + 4u;
  TFR(13) TFR(15) TFR(26) TFR(6)   x0 += k2; x1 += k0 + 5u;
#undef TFR
  o0 = x0; o1 = x1;
}

// ---- host tables (pure constants; computed once at library load) ----
struct HostTables {
  RC rcs[5];
  uint32_t kp0[5], kp1[5];
  HostTables() {
    static const int Hs[5] = {256, 128, 64, 32, 16};
    for (int l = 0; l < 5; ++l) {
      uint32_t f0, f1;
      tf2x32(0u, 42u, 0u, (uint32_t)l, f0, f1);  // fold_in(key(42), l)
      uint32_t ik0, ik1;
      tf2x32(f0, f1, 0u, 0u, ik0, ik1);          // k_idx = split[0]
      tf2x32(f0, f1, 0u, 1u, kp0[l], kp1[l]);    // k_proj = split[1]
      int Wm6 = Hs[l] - 6;
      int n = Wm6 * Wm6;
      int nd = n < 128 ? n : 128;
      std::vector<int> perm(n);
      std::iota(perm.begin(), perm.end(), 0);
      int rounds = (int)std::ceil(3.0 * std::log((double)n) / std::log(4294967295.0));
      uint32_t key0 = ik0, key1 = ik1;
      std::vector<uint32_t> bits(n);
      std::vector<int> ord(n), tmp(n);
      for (int r = 0; r < rounds; ++r) {
        uint32_t nk0, nk1, s0, s1;
        tf2x32(key0, key1, 0u, 0u, nk0, nk1);
        tf2x32(key0, key1, 0u, 1u, s0, s1);
        key0 = nk0; key1 = nk1;
        for (int tt = 0; tt < n; ++tt) {
          uint32_t o0, o1;
          tf2x32(s0, s1, 0u, (uint32_t)tt, o0, o1);
          bits[tt] = o0 ^ o1;
        }
        std::iota(ord.begin(), ord.end(), 0);
        std::stable_sort(ord.begin(), ord.end(),
                         [&](int A, int B) { return bits[A] < bits[B]; });
        for (int i2 = 0; i2 < n; ++i2) tmp[i2] = perm[ord[i2]];
        perm.swap(tmp);
      }
      for (int d = 0; d < 128; ++d) {
        int vv = (d < nd) ? perm[d] : 0;
        rcs[l].rc[d] = ((uint32_t)(vv / Wm6) << 16) | (uint32_t)(vv % Wm6);
      }
    }
  }
};
static const HostTables g_tbl;

__device__ inline float erfinv_f(float x) {
  float w = -log1pf(-x * x);
  float p;
  if (w < 5.0f) {
    w = w - 2.5f;
    p = 2.81022636e-08f;
    p = fmaf(p, w, 3.43273939e-07f);
    p = fmaf(p, w, -3.5233877e-06f);
    p = fmaf(p, w, -4.39150654e-06f);
    p = fmaf(p, w, 0.00021858087f);
    p = fmaf(p, w, -0.00125372503f);
    p = fmaf(p, w, -0.00417768164f);
    p = fmaf(p, w, 0.246640727f);
    p = fmaf(p, w, 1.50140941f);
  } else {
    w = sqrtf(w) - 3.0f;
    p = -0.000200214257f;
    p = fmaf(p, w, 0.000100950558f);
    p = fmaf(p, w, 0.00134934322f);
    p = fmaf(p, w, -0.00367342844f);
    p = fmaf(p, w, 0.00573950773f);
    p = fmaf(p, w, -0.0076224613f);
    p = fmaf(p, w, 0.00943887047f);
    p = fmaf(p, w, 1.00167406f);
    p = fmaf(p, w, 2.83297682f);
  }
  return p * x;
}

__device__ inline float bits_to_normal(uint32_t b) {
  union { uint32_t u; float f; } cv;
  cv.u = (b >> 9) | 0x3f800000u;
  float f = cv.f - 1.0f;
  const float lo = -0.99999994f;
  const float span = 1.0f - lo;
  float u = fmaxf(lo, __fadd_rn(__fmul_rn(f, span), lo));
  return 1.41421356237f * erfinv_f(u);
}

// ---- kernels ----

__global__ void init_kernel(float* m) {
  int i = threadIdx.x;
  if (i < 128) m[i] = 0.f;
}

__global__ __launch_bounds__(256) void down_kernel(
    const float* __restrict__ in, float* __restrict__ out,
    int H, int W, int total) {
  int idx = blockIdx.x * 256 + threadIdx.x;
  if (idx >= total) return;
  int Wo = W >> 1, Ho = H >> 1;
  int ox = idx % Wo;
  int t = idx / Wo;
  int oy = t % Ho;
  int bc = t / Ho;
  const float* src = in + (size_t)bc * H * W;
  float s = 0.f;
#pragma unroll
  for (int u = 0; u < 5; ++u) {
    int y = 2 * oy + u - 2;
    if (y < 0 || y >= H) continue;
    const float* r = src + (size_t)y * W;
#pragma unroll
    for (int v = 0; v < 5; ++v) {
      int x = 2 * ox + v - 2;
      if (x < 0 || x >= W) continue;
      s += KW[u] * KW[v] * r[x];
    }
  }
  out[idx] = s;
}

__global__ void randgen_kernel(float* __restrict__ rnd, uint32_t k0, uint32_t k1) {
  int t = blockIdx.x * 256 + threadIdx.x;  // grid covers 81920
  const int total = 75264;                 // 147*512
  if (t < total) {
    uint32_t o0, o1;
    tf2x32(k0, k1, 0u, (uint32_t)t, o0, o1);
    rnd[t] = bits_to_normal(o0 ^ o1);
  }
}

// extract + per-channel stats (sum, sumsq); grid-stride, per-block partials
// to part[blockIdx*6 + {c, 3+c}] -- NO global atomics.
__global__ __launch_bounds__(256) void extract_kernel(
    const float* __restrict__ g, const float* __restrict__ gn,
    float* __restrict__ p, float* __restrict__ part, RC rcs,
    int H, int nd, int useLap, int total) {
  __shared__ float ls[6];
  if (threadIdx.x < 6) ls[threadIdx.x] = 0.f;
  __syncthreads();
  for (int idx = blockIdx.x * 256 + threadIdx.x; idx < total; idx += ENB * 256) {
    int col = idx % 160;
    if (col < 147) {
      int row = idx / 160;
      int d = row % nd, b = row / nd;
      int c = col / 49, uv = col % 49, u = uv / 7, v = uv % 7;
      unsigned rc = rcs.rc[d];
      int y = (int)(rc >> 16) + u;
      int x = (int)(rc & 0xffffu) + v;
      const float* gc = g + ((size_t)(b * 3 + c)) * H * H;
      float val = gc[(size_t)y * H + x];
      if (useLap) {
        int H2 = H >> 1;
        const float* gnc = gn + ((size_t)(b * 3 + c)) * H2 * H2;
        int h = y >> 1, w = x >> 1;
        int yo = y & 1, xo = x & 1;
        float rw0 = (y >= 2) ? (yo ? 0.0625f : 0.3125f) : 0.f;
        float rw2 = (y <= H - 3) ? (yo ? 0.3125f : 0.0625f) : 0.f;
        float cw0 = (x >= 2) ? (xo ? 0.0625f : 0.3125f) : 0.f;
        float cw2 = (x <= H - 3) ? (xo ? 0.3125f : 0.0625f) : 0.f;
        int r0 = max(h - 1, 0), r2 = min(h + 1, H2 - 1);
        int c0 = max(w - 1, 0), c2 = min(w + 1, H2 - 1);
        const float* R0 = gnc + (size_t)r0 * H2;
        const float* R1 = gnc + (size_t)h * H2;
        const float* R2 = gnc + (size_t)r2 * H2;
        float s0 = cw0 * R0[c0] + 0.625f * R0[w] + cw2 * R0[c2];
        float s1 = cw0 * R1[c0] + 0.625f * R1[w] + cw2 * R1[c2];
        float s2 = cw0 * R2[c0] + 0.625f * R2[w] + cw2 * R2[c2];
        val -= rw0 * s0 + 0.625f * s1 + rw2 * s2;
      }
      p[idx] = val;
      atomicAdd(&ls[c], val);
      atomicAdd(&ls[3 + c], val * val);
    }
  }
  __syncthreads();
  if (threadIdx.x < 6) part[blockIdx.x * 6 + threadIdx.x] = ls[threadIdx.x];
}

// reduce ENB-block partials, then build projection matrices + bias
__global__ void prep_kernel(const float* __restrict__ rnd,
                            const float* __restrict__ part1,
                            const float* __restrict__ part2,
                            float* __restrict__ B1, float* __restrict__ B2,
                            float* __restrict__ bias, float Np) {
  __shared__ float red[12];
  int tid = threadIdx.x;
  if (tid < 12) red[tid] = 0.f;
  __syncthreads();
  if (tid < 192) {
    int k = tid >> 4, r0 = tid & 15;        // 12 groups x 16 threads; 2048%16==0
    const float* src = (k < 6) ? part1 : part2;
    int kk = (k < 6) ? k : k - 6;
    float ssum = 0.f;
    for (int r = r0; r < ENB; r += 16) ssum += src[r * 6 + kk];
    atomicAdd(&red[k], ssum);
  }
  __syncthreads();
  int j = blockIdx.x * 256 + tid;
  if (j >= 512) return;
  float sum = 0.f, q = 0.f;
  for (int f = 0; f < 147; ++f) {
    float v = rnd[f * 512 + j];
    sum += v; q = fmaf(v, v, q);
  }
  float mean = sum * (1.f / 147.f);
  float var = (q - 147.f * mean * mean) * (1.f / 146.f);
  float inv1 = 1.f / sqrtf(var);
  float b1 = 0.f, b2 = 0.f;
#pragma unroll
  for (int c = 0; c < 3; ++c) {
    float m1 = red[c] / Np;
    float v1 = (red[3 + c] - Np * m1 * m1) / (Np - 1.f);
    float i1 = 1.f / (sqrtf(fmaxf(v1, 0.f)) + 1e-8f);
    float m2 = red[6 + c] / Np;
    float v2 = (red[9 + c] - Np * m2 * m2) / (Np - 1.f);
    float i2 = 1.f / (sqrtf(fmaxf(v2, 0.f)) + 1e-8f);
    for (int ff = 0; ff < 49; ++ff) {
      int f = c * 49 + ff;
      float rv = rnd[f * 512 + j] * inv1;
      float w1 = rv * i1; B1[f * 512 + j] = w1; b1 = fmaf(m1, w1, b1);
      float w2 = rv * i2; B2[f * 512 + j] = w2; b2 = fmaf(m2, w2, b2);
    }
  }
  for (int f = 147; f < 160; ++f) { B1[f * 512 + j] = 0.f; B2[f * 512 + j] = 0.f; }
  bias[j] = b1; bias[512 + j] = b2;
}

// C[n][m] col-major (stride 16384) = A[M][160] * B[160][512] - bias[n]
#define GBM 128
#define GBN 128
#define GBK 16
__global__ __launch_bounds__(256) void gemm_kernel(
    const float* __restrict__ A, const float* __restrict__ B,
    const float* __restrict__ bias, float* __restrict__ C, int M) {
  __shared__ __align__(16) float As[GBK][GBM + 4];
  __shared__ __align__(16) float Bs[GBK][GBN];
  int bm = blockIdx.x * GBM;
  int bn = blockIdx.y * GBN;
  int tid = threadIdx.x;
  int tm = tid & 15;
  int tn = tid >> 4;
  float acc[8][8] = {{0.f}};
  for (int k0 = 0; k0 < 160; k0 += GBK) {
#pragma unroll
    for (int i = 0; i < 2; ++i) {
      int q = tid + i * 256;
      int r = q >> 2, c4 = (q & 3) << 2;
      float4 va = *(const float4*)(A + (size_t)(bm + r) * 160 + k0 + c4);
      As[c4 + 0][r] = va.x; As[c4 + 1][r] = va.y;
      As[c4 + 2][r] = va.z; As[c4 + 3][r] = va.w;
    }
#pragma unroll
    for (int i = 0; i < 2; ++i) {
      int q = tid + i * 256;
      int r = q >> 5, c = (q & 31) << 2;
      *(float4*)(&Bs[r][c]) = *(const float4*)(B + (size_t)(k0 + r) * 512 + bn + c);
    }
    __syncthreads();
#pragma unroll
    for (int kk = 0; kk < GBK; ++kk) {
      float4 a0 = *(const float4*)(&As[kk][tm * 8]);
      float4 a1 = *(const float4*)(&As[kk][tm * 8 + 4]);
      float4 b0 = *(const float4*)(&Bs[kk][tn * 8]);
      float4 b1 = *(const float4*)(&Bs[kk][tn * 8 + 4]);
      float av[8] = {a0.x, a0.y, a0.z, a0.w, a1.x, a1.y, a1.z, a1.w};
      float bv[8] = {b0.x, b0.y, b0.z, b0.w, b1.x, b1.y, b1.z, b1.w};
#pragma unroll
      for (int i = 0; i < 8; ++i)
#pragma unroll
        for (int jj = 0; jj < 8; ++jj)
          acc[i][jj] = fmaf(av[i], bv[jj], acc[i][jj]);
    }
    __syncthreads();
  }
#pragma unroll
  for (int jj = 0; jj < 8; ++jj) {
    int n = bn + tn * 8 + jj;
    float bb = bias[n];
    float4 v0 = make_float4(acc[0][jj] - bb, acc[1][jj] - bb, acc[2][jj] - bb, acc[3][jj] - bb);
    float4 v1 = make_float4(acc[4][jj] - bb, acc[5][jj] - bb, acc[6][jj] - bb, acc[7][jj] - bb);
    float* cp = C + (size_t)n * 16384 + bm + tm * 8;
    *(float4*)cp = v0;
    *(float4*)(cp + 4) = v1;
  }
}

// ---- merge-path sort + diff (bank-swizzled LDS) ----
// co-rank: smallest i in [max(0,so-L), min(so,L)] s.t. merged prefix of size
// so takes i from A, so-i from B. Convention: advance while A[i] < B[so-1-i].
__device__ inline int corank(const float* __restrict__ s, int pb, int L, int so) {
  int lo = so - L; lo = lo < 0 ? 0 : lo;
  int hi = so < L ? so : L;
  while (lo < hi) {
    int mid = (lo + hi) >> 1;
    float a = s[SIDX(pb + mid)];
    float b = s[SIDX(pb + L + so - 1 - mid)];
    if (a < b) lo = mid + 1; else hi = mid;
  }
  return lo;
}

// One merge-path round: v holds this thread's 16 values of a sorted run of
// length L; after the call v holds its 16 values of the merged 2L run.
// crosswave=false (L<=512): window 2L fits in this wave's 1024-elem segment,
// no block barrier needed (wave64 lockstep + in-order DS pipe).
// crosswave=true: write;sync;read;sync.
__device__ __forceinline__ void merge_round(float (&v)[16], float* __restrict__ s,
                                            int t, int bi, int L, bool crosswave) {
  // staging: this thread's 16 elements share one 32-row -> constant XOR;
  // addresses are a permuted contiguous 16-block (conflict-free).
  int sw = (bi >> 5) & 31;
#pragma unroll
  for (int q = 0; q < 16; ++q) s[(bi + q) ^ sw] = v[q];
  if (crosswave) __syncthreads();
  else __builtin_amdgcn_wave_barrier();
  int pb = bi & ~(2 * L - 1);
  int so = bi - pb;
  int i0 = corank(s, pb, L, so);
  int nxt = __shfl_down(i0, 1, 64);   // lane t+1's i0 == our i1
  int i1;
  if (((so + 16) & (2 * L - 1)) == 0) i1 = L;              // last window slot
  else if (crosswave && (t & 63) == 63) i1 = corank(s, pb, L, so + 16);
  else i1 = nxt;
  int na = i1 - i0;
  int j1 = so + 16 - i1;
#pragma unroll
  for (int q = 0; q < 16; ++q) {
    int idx = (q < na) ? (pb + i0 + q)
                       : (pb + L + j1 - 1 - (q - na));
    v[q] = s[SIDX(idx)];
  }
  // window = ascending A-part then descending B-part => bitonic; merge up
#pragma unroll
  for (int j = 8; j >= 1; j >>= 1) {
#pragma unroll
    for (int q = 0; q < 16; ++q) {
      if ((q & j) == 0) {
        float a = v[q], b = v[q | j];
        v[q] = fminf(a, b);
        v[q | j] = fmaxf(a, b);
      }
    }
  }
  if (crosswave) __syncthreads();
}

// full 16384-element sort of one column (entry: v = 16 ascending-sorted
// values at positions bi..bi+15). Exits with all threads synced.
__device__ __forceinline__ void mergesort_col(float (&v)[16], float* __restrict__ s,
                                              int t, int bi) {
  for (int L = 16; L <= 512; L <<= 1) merge_round(v, s, t, bi, L, false);
  for (int L = 1024; L <= 8192; L <<= 1) merge_round(v, s, t, bi, L, true);
}

__global__ __launch_bounds__(1024, 8) void sortdiff_kernel(
    const float* __restrict__ proj1, const float* __restrict__ proj2,
    float* __restrict__ sum, int m) {
  __shared__ float s[16384];
  int t = threadIdx.x;
  int col = blockIdx.x;  // 0..511
  const float INF = __builtin_huge_valf();
  float va[16], vb[16];
  int bi = t << 4;

  const float* pa = proj1 + (size_t)col * 16384;
  const float* pbp = proj2 + (size_t)col * 16384;
  if (bi < m) {
#pragma unroll
    for (int i = 0; i < 4; ++i) {
      float4 A4 = *(const float4*)(pa + bi + i * 4);
      va[i * 4 + 0] = A4.x; va[i * 4 + 1] = A4.y;
      va[i * 4 + 2] = A4.z; va[i * 4 + 3] = A4.w;
      float4 B4 = *(const float4*)(pbp + bi + i * 4);
      vb[i * 4 + 0] = B4.x; vb[i * 4 + 1] = B4.y;
      vb[i * 4 + 2] = B4.z; vb[i * 4 + 3] = B4.w;
    }
  } else {
#pragma unroll
    for (int r = 0; r < 16; ++r) { va[r] = INF; vb[r] = INF; }
  }

  // ---- in-thread bitonic-16 sort, both columns interleaved (2x ILP)
#pragma unroll
  for (int k = 2; k <= 16; k <<= 1) {
#pragma unroll
    for (int j = k >> 1; j >= 1; j >>= 1) {
#pragma unroll
      for (int r = 0; r < 16; ++r) {
        if ((r & j) == 0) {
          bool up = ((r & k) == 0);   // k=16: always true for r<16
          float a0 = va[r], b0 = va[r | j];
          float lo0 = fminf(a0, b0), hi0 = fmaxf(a0, b0);
          va[r] = up ? lo0 : hi0;
          va[r | j] = up ? hi0 : lo0;
          float a1 = vb[r], b1 = vb[r | j];
          float lo1 = fminf(a1, b1), hi1 = fmaxf(a1, b1);
          vb[r] = up ? lo1 : hi1;
          vb[r | j] = up ? hi1 : lo1;
        }
      }
    }
  }

  // column A: 10 merge-path rounds; result stays in va. exits synced.
  mergesort_col(va, s, t, bi);
  // column B: reuse LDS; result lands in vb.
  mergesort_col(vb, s, t, bi);

  float acc = 0.f;
  if (bi < m) {
#pragma unroll
    for (int q = 0; q < 16; ++q) acc += fabsf(va[q] - vb[q]);
  }

#pragma unroll
  for (int o = 32; o > 0; o >>= 1) acc += __shfl_down(acc, o, 64);
  if ((t & 63) == 0) s[t >> 6] = acc;
  __syncthreads();
  if (t == 0) {
    float tot = 0.f;
    for (int i = 0; i < 16; ++i) tot += s[i];
    atomicAdd(sum, tot);
  }
}

__global__ void final_kernel(const float* __restrict__ sums, float* __restrict__ out) {
  float r = sums[0] * (1.f / 8388608.f) + sums[1] * (1.f / 8388608.f) +
            sums[2] * (1.f / 8388608.f) + sums[3] * (1.f / 8388608.f) +
            sums[4] * (1.f / 6553600.f);
  out[0] = r * (1000.f / 5.f);
}

// ---------------------------------------------------------------------------

extern "C" void kernel_launch(void* const* d_in, const int* in_sizes, int n_in,
                              void* d_out, int out_size, void* d_ws, size_t ws_size,
                              hipStream_t stream) {
  const float* xin = (const float*)d_in[0];
  const float* yin = (const float*)d_in[1];
  float* out = (float*)d_out;

  char* base = (char*)d_ws;
  size_t off = 0;
  auto alloc = [&](size_t nfloats) -> float* {
    float* p = (float*)(base + off);
    off += ((nfloats * 4) + 255) & ~(size_t)255;
    return p;
  };
  float* gX[5];
  float* gY[5];
  gX[0] = (float*)xin;
  gY[0] = (float*)yin;
  gX[1] = alloc(6291456); gX[2] = alloc(1572864); gX[3] = alloc(393216); gX[4] = alloc(98304);
  gY[1] = alloc(6291456); gY[2] = alloc(1572864); gY[3] = alloc(393216); gY[4] = alloc(98304);
  float* p1 = alloc((size_t)16384 * 160);
  float* p2 = alloc((size_t)16384 * 160);
  float* rnd = alloc(160 * 512);
  float* B1 = alloc(160 * 512);
  float* B2 = alloc(160 * 512);
  float* biasb = alloc(1024);
  float* proj1 = alloc((size_t)16384 * 512);
  float* proj2 = alloc((size_t)16384 * 512);
  float* part1 = alloc(ENB * 6);
  float* part2 = alloc(ENB * 6);
  float* misc = alloc(128);

  static const int Hs[5] = {256, 128, 64, 32, 16};

  init_kernel<<<1, 128, 0, stream>>>(misc);
  for (int t = 0; t < 2; ++t) {
    const float* in0 = t ? yin : xin;
    float** g = t ? gY : gX;
    down_kernel<<<(384 * 128 * 128 + 255) / 256, 256, 0, stream>>>(in0, g[1], 256, 256, 384 * 128 * 128);
    down_kernel<<<(384 * 64 * 64 + 255) / 256, 256, 0, stream>>>(g[1], g[2], 128, 128, 384 * 64 * 64);
    down_kernel<<<(384 * 32 * 32 + 255) / 256, 256, 0, stream>>>(g[2], g[3], 64, 64, 384 * 32 * 32);
    down_kernel<<<(384 * 16 * 16 + 255) / 256, 256, 0, stream>>>(g[3], g[4], 32, 32, 384 * 16 * 16);
  }
  for (int l = 0; l < 5; ++l) {
    int H = Hs[l];
    int Wm6 = H - 6;
    int n = Wm6 * Wm6;
    int nd = n < 128 ? n : 128;
    int M = 128 * nd;
    randgen_kernel<<<320, 256, 0, stream>>>(rnd, g_tbl.kp0[l], g_tbl.kp1[l]);
    int totalE = M * 160;
    extract_kernel<<<ENB, 256, 0, stream>>>(
        gX[l], (l < 4) ? gX[l + 1] : nullptr, p1, part1, g_tbl.rcs[l], H, nd, (l < 4) ? 1 : 0, totalE);
    extract_kernel<<<ENB, 256, 0, stream>>>(
        gY[l], (l < 4) ? gY[l + 1] : nullptr, p2, part2, g_tbl.rcs[l], H, nd, (l < 4) ? 1 : 0, totalE);
    prep_kernel<<<2, 256, 0, stream>>>(rnd, part1, part2, B1, B2, biasb, (float)M * 49.f);
    dim3 gg(M / 128, 4);
    gemm_kernel<<<gg, 256, 0, stream>>>(p1, B1, biasb, proj1, M);
    gemm_kernel<<<gg, 256, 0, stream>>>(p2, B2, biasb + 512, proj2, M);
    sortdiff_kernel<<<512, 1024, 0, stream>>>(proj1, proj2, misc + l, M);
  }
  final_kernel<<<1, 1, 0, stream>>>(misc, out);
}

// Round 7
// 1962.110 us; speedup vs baseline: 1.6036x; 1.0295x over previous
//
#include <hip/hip_runtime.h>
#include <hip/hip_bf16.h>
#include <cstdint>
#include <cmath>
#include <vector>
#include <algorithm>
#include <numeric>

// ---------------------------------------------------------------------------
// LapSWD loss. RNG = exact JAX partitionable threefry (verified absmax 0.0).
// R12 = R11 resubmitted verbatim (R11 bench was an infra failure: "MI355X
// container failed twice" -- no compile/run evidence against the kernel).
// R11: dispatch-geometry round. X+Y fused into single dispatches:
//  - gemm: gridDim.z=2 (p1/B1->proj1, p2/B2->proj2): 2 -> 4 blocks/CU; the
//    gemm is LDS-throughput-bound (61k DS cyc vs 41k VALU cyc per CU) and the
//    extra resident blocks feed the DS pipe across __syncthreads bubbles.
//  - extract: one 2*ENB-block dispatch (halves select X/Y), doubling resident
//    scattered-load waves (latency-bound kernel).
//  - down: one dispatch per level for both pyramids.
//  - randgen: all 5 levels in one dispatch (+ inlined misc zeroing).
// Launches 46 -> 27. Sort path (R7 merge-path + R8 swizzle + R10 partials)
// unchanged.
// ---------------------------------------------------------------------------

#define SIDX(i) ((i) ^ (((i) >> 5) & 31))
#define ENB 2048  // extract grid per half: 2048 blocks x 256 thr, grid-stride

__constant__ float KW[5] = {0.0625f, 0.25f, 0.375f, 0.25f, 0.0625f};

struct RC { unsigned int rc[128]; };
struct Keys { uint32_t a[5]; uint32_t b[5]; };

// ---- threefry2x32 block cipher, exact JAX/XLA schedule ----
__host__ __device__ inline void tf2x32(uint32_t k0, uint32_t k1,
                                       uint32_t x0, uint32_t x1,
                                       uint32_t& o0, uint32_t& o1) {
  uint32_t k2 = k0 ^ k1 ^ 0x1BD11BDAu;
  x0 += k0; x1 += k1;
#define TFR(r) { x0 += x1; x1 = (x1 << r) | (x1 >> (32 - r)); x1 ^= x0; }
  TFR(13) TFR(15) TFR(26) TFR(6)   x0 += k1; x1 += k2 + 1u;
  TFR(17) TFR(29) TFR(16) TFR(24)  x0 += k2; x1 += k0 + 2u;
  TFR(13) TFR(15) TFR(26) TFR(6)   x0 += k0; x1 += k1 + 3u;
  TFR(17) TFR(29) TFR(16) TFR(24)  x0 += k1; x1 += k2 + 4u;
  TFR(13) TFR(15) TFR(26) TFR(6)   x0 += k2; x1 += k0 + 5u;
#undef TFR
  o0 = x0; o1 = x1;
}

// ---- host tables (pure constants; computed once at library load) ----
struct HostTables {
  RC rcs[5];
  uint32_t kp0[5], kp1[5];
  HostTables() {
    static const int Hs[5] = {256, 128, 64, 32, 16};
    for (int l = 0; l < 5; ++l) {
      uint32_t f0, f1;
      tf2x32(0u, 42u, 0u, (uint32_t)l, f0, f1);  // fold_in(key(42), l)
      uint32_t ik0, ik1;
      tf2x32(f0, f1, 0u, 0u, ik0, ik1);          // k_idx = split[0]
      tf2x32(f0, f1, 0u, 1u, kp0[l], kp1[l]);    // k_proj = split[1]
      int Wm6 = Hs[l] - 6;
      int n = Wm6 * Wm6;
      int nd = n < 128 ? n : 128;
      std::vector<int> perm(n);
      std::iota(perm.begin(), perm.end(), 0);
      int rounds = (int)std::ceil(3.0 * std::log((double)n) / std::log(4294967295.0));
      uint32_t key0 = ik0, key1 = ik1;
      std::vector<uint32_t> bits(n);
      std::vector<int> ord(n), tmp(n);
      for (int r = 0; r < rounds; ++r) {
        uint32_t nk0, nk1, s0, s1;
        tf2x32(key0, key1, 0u, 0u, nk0, nk1);
        tf2x32(key0, key1, 0u, 1u, s0, s1);
        key0 = nk0; key1 = nk1;
        for (int tt = 0; tt < n; ++tt) {
          uint32_t o0, o1;
          tf2x32(s0, s1, 0u, (uint32_t)tt, o0, o1);
          bits[tt] = o0 ^ o1;
        }
        std::iota(ord.begin(), ord.end(), 0);
        std::stable_sort(ord.begin(), ord.end(),
                         [&](int A, int B) { return bits[A] < bits[B]; });
        for (int i2 = 0; i2 < n; ++i2) tmp[i2] = perm[ord[i2]];
        perm.swap(tmp);
      }
      for (int d = 0; d < 128; ++d) {
        int vv = (d < nd) ? perm[d] : 0;
        rcs[l].rc[d] = ((uint32_t)(vv / Wm6) << 16) | (uint32_t)(vv % Wm6);
      }
    }
  }
};
static const HostTables g_tbl;

__device__ inline float erfinv_f(float x) {
  float w = -log1pf(-x * x);
  float p;
  if (w < 5.0f) {
    w = w - 2.5f;
    p = 2.81022636e-08f;
    p = fmaf(p, w, 3.43273939e-07f);
    p = fmaf(p, w, -3.5233877e-06f);
    p = fmaf(p, w, -4.39150654e-06f);
    p = fmaf(p, w, 0.00021858087f);
    p = fmaf(p, w, -0.00125372503f);
    p = fmaf(p, w, -0.00417768164f);
    p = fmaf(p, w, 0.246640727f);
    p = fmaf(p, w, 1.50140941f);
  } else {
    w = sqrtf(w) - 3.0f;
    p = -0.000200214257f;
    p = fmaf(p, w, 0.000100950558f);
    p = fmaf(p, w, 0.00134934322f);
    p = fmaf(p, w, -0.00367342844f);
    p = fmaf(p, w, 0.00573950773f);
    p = fmaf(p, w, -0.0076224613f);
    p = fmaf(p, w, 0.00943887047f);
    p = fmaf(p, w, 1.00167406f);
    p = fmaf(p, w, 2.83297682f);
  }
  return p * x;
}

__device__ inline float bits_to_normal(uint32_t b) {
  union { uint32_t u; float f; } cv;
  cv.u = (b >> 9) | 0x3f800000u;
  float f = cv.f - 1.0f;
  const float lo = -0.99999994f;
  const float span = 1.0f - lo;
  float u = fmaxf(lo, __fadd_rn(__fmul_rn(f, span), lo));
  return 1.41421356237f * erfinv_f(u);
}

// ---- kernels ----

// X and Y pyramids in one dispatch: idx < total -> X, else -> Y.
__global__ __launch_bounds__(256) void down_kernel(
    const float* __restrict__ inX, float* __restrict__ outX,
    const float* __restrict__ inY, float* __restrict__ outY,
    int H, int W, int total) {
  int idx = blockIdx.x * 256 + threadIdx.x;
  if (idx >= 2 * total) return;
  const float* in = inX;
  float* out = outX;
  if (idx >= total) { idx -= total; in = inY; out = outY; }
  int Wo = W >> 1, Ho = H >> 1;
  int ox = idx % Wo;
  int t = idx / Wo;
  int oy = t % Ho;
  int bc = t / Ho;
  const float* src = in + (size_t)bc * H * W;
  float s = 0.f;
#pragma unroll
  for (int u = 0; u < 5; ++u) {
    int y = 2 * oy + u - 2;
    if (y < 0 || y >= H) continue;
    const float* r = src + (size_t)y * W;
#pragma unroll
    for (int v = 0; v < 5; ++v) {
      int x = 2 * ox + v - 2;
      if (x < 0 || x >= W) continue;
      s += KW[u] * KW[v] * r[x];
    }
  }
  out[idx] = s;
}

// all 5 levels' random projection bits in one dispatch; block 0 also zeroes misc
__global__ void randgen_kernel(float* __restrict__ rnd, Keys ks,
                               float* __restrict__ misc) {
  int t = blockIdx.x * 256 + threadIdx.x;   // 1470 blocks = 376320 = 5*75264
  if (blockIdx.x == 0 && threadIdx.x < 128) misc[threadIdx.x] = 0.f;
  const int per = 75264;                    // 147*512
  int l = t / per;
  int tt = t - l * per;
  if (l < 5) {
    uint32_t o0, o1;
    tf2x32(ks.a[l], ks.b[l], 0u, (uint32_t)tt, o0, o1);
    rnd[l * per + tt] = bits_to_normal(o0 ^ o1);
  }
}

// extract + per-channel stats (sum, sumsq); X and Y halves in one dispatch;
// grid-stride per half, per-block partials -- NO global atomics.
__global__ __launch_bounds__(256) void extract_kernel(
    const float* __restrict__ g1, const float* __restrict__ gn1,
    float* __restrict__ p1g, float* __restrict__ part1,
    const float* __restrict__ g2, const float* __restrict__ gn2,
    float* __restrict__ p2g, float* __restrict__ part2,
    RC rcs, int H, int nd, int useLap, int total) {
  __shared__ float ls[6];
  if (threadIdx.x < 6) ls[threadIdx.x] = 0.f;
  __syncthreads();
  int half = (blockIdx.x >= ENB) ? 1 : 0;
  int bid = blockIdx.x - half * ENB;
  const float* g = half ? g2 : g1;
  const float* gn = half ? gn2 : gn1;
  float* p = half ? p2g : p1g;
  float* part = half ? part2 : part1;
  for (int idx = bid * 256 + threadIdx.x; idx < total; idx += ENB * 256) {
    int col = idx % 160;
    if (col < 147) {
      int row = idx / 160;
      int d = row % nd, b = row / nd;
      int c = col / 49, uv = col % 49, u = uv / 7, v = uv % 7;
      unsigned rc = rcs.rc[d];
      int y = (int)(rc >> 16) + u;
      int x = (int)(rc & 0xffffu) + v;
      const float* gc = g + ((size_t)(b * 3 + c)) * H * H;
      float val = gc[(size_t)y * H + x];
      if (useLap) {
        int H2 = H >> 1;
        const float* gnc = gn + ((size_t)(b * 3 + c)) * H2 * H2;
        int h = y >> 1, w = x >> 1;
        int yo = y & 1, xo = x & 1;
        float rw0 = (y >= 2) ? (yo ? 0.0625f : 0.3125f) : 0.f;
        float rw2 = (y <= H - 3) ? (yo ? 0.3125f : 0.0625f) : 0.f;
        float cw0 = (x >= 2) ? (xo ? 0.0625f : 0.3125f) : 0.f;
        float cw2 = (x <= H - 3) ? (xo ? 0.3125f : 0.0625f) : 0.f;
        int r0 = max(h - 1, 0), r2 = min(h + 1, H2 - 1);
        int c0 = max(w - 1, 0), c2 = min(w + 1, H2 - 1);
        const float* R0 = gnc + (size_t)r0 * H2;
        const float* R1 = gnc + (size_t)h * H2;
        const float* R2 = gnc + (size_t)r2 * H2;
        float s0 = cw0 * R0[c0] + 0.625f * R0[w] + cw2 * R0[c2];
        float s1 = cw0 * R1[c0] + 0.625f * R1[w] + cw2 * R1[c2];
        float s2 = cw0 * R2[c0] + 0.625f * R2[w] + cw2 * R2[c2];
        val -= rw0 * s0 + 0.625f * s1 + rw2 * s2;
      }
      p[idx] = val;
      atomicAdd(&ls[c], val);
      atomicAdd(&ls[3 + c], val * val);
    }
  }
  __syncthreads();
  if (threadIdx.x < 6) part[bid * 6 + threadIdx.x] = ls[threadIdx.x];
}

// reduce ENB-block partials, then build projection matrices + bias
__global__ void prep_kernel(const float* __restrict__ rnd,
                            const float* __restrict__ part1,
                            const float* __restrict__ part2,
                            float* __restrict__ B1, float* __restrict__ B2,
                            float* __restrict__ bias, float Np) {
  __shared__ float red[12];
  int tid = threadIdx.x;
  if (tid < 12) red[tid] = 0.f;
  __syncthreads();
  if (tid < 192) {
    int k = tid >> 4, r0 = tid & 15;        // 12 groups x 16 threads; 2048%16==0
    const float* src = (k < 6) ? part1 : part2;
    int kk = (k < 6) ? k : k - 6;
    float ssum = 0.f;
    for (int r = r0; r < ENB; r += 16) ssum += src[r * 6 + kk];
    atomicAdd(&red[k], ssum);
  }
  __syncthreads();
  int j = blockIdx.x * 256 + tid;
  if (j >= 512) return;
  float sum = 0.f, q = 0.f;
  for (int f = 0; f < 147; ++f) {
    float v = rnd[f * 512 + j];
    sum += v; q = fmaf(v, v, q);
  }
  float mean = sum * (1.f / 147.f);
  float var = (q - 147.f * mean * mean) * (1.f / 146.f);
  float inv1 = 1.f / sqrtf(var);
  float b1 = 0.f, b2 = 0.f;
#pragma unroll
  for (int c = 0; c < 3; ++c) {
    float m1 = red[c] / Np;
    float v1 = (red[3 + c] - Np * m1 * m1) / (Np - 1.f);
    float i1 = 1.f / (sqrtf(fmaxf(v1, 0.f)) + 1e-8f);
    float m2 = red[6 + c] / Np;
    float v2 = (red[9 + c] - Np * m2 * m2) / (Np - 1.f);
    float i2 = 1.f / (sqrtf(fmaxf(v2, 0.f)) + 1e-8f);
    for (int ff = 0; ff < 49; ++ff) {
      int f = c * 49 + ff;
      float rv = rnd[f * 512 + j] * inv1;
      float w1 = rv * i1; B1[f * 512 + j] = w1; b1 = fmaf(m1, w1, b1);
      float w2 = rv * i2; B2[f * 512 + j] = w2; b2 = fmaf(m2, w2, b2);
    }
  }
  for (int f = 147; f < 160; ++f) { B1[f * 512 + j] = 0.f; B2[f * 512 + j] = 0.f; }
  bias[j] = b1; bias[512 + j] = b2;
}

// C[n][m] col-major (stride 16384) = A[M][160] * B[160][512] - bias[n]
// blockIdx.z selects (p1,B1,bias,proj1) vs (p2,B2,bias+512,proj2)
#define GBM 128
#define GBN 128
#define GBK 16
__global__ __launch_bounds__(256) void gemm_kernel(
    const float* __restrict__ A1, const float* __restrict__ Bm1,
    const float* __restrict__ A2, const float* __restrict__ Bm2,
    const float* __restrict__ bias, float* __restrict__ C1,
    float* __restrict__ C2, int M) {
  __shared__ __align__(16) float As[GBK][GBM + 4];
  __shared__ __align__(16) float Bs[GBK][GBN];
  int z = blockIdx.z;
  const float* A = z ? A2 : A1;
  const float* B = z ? Bm2 : Bm1;
  const float* bp = bias + (z ? 512 : 0);
  float* C = z ? C2 : C1;
  int bm = blockIdx.x * GBM;
  int bn = blockIdx.y * GBN;
  int tid = threadIdx.x;
  int tm = tid & 15;
  int tn = tid >> 4;
  float acc[8][8] = {{0.f}};
  for (int k0 = 0; k0 < 160; k0 += GBK) {
#pragma unroll
    for (int i = 0; i < 2; ++i) {
      int q = tid + i * 256;
      int r = q >> 2, c4 = (q & 3) << 2;
      float4 va = *(const float4*)(A + (size_t)(bm + r) * 160 + k0 + c4);
      As[c4 + 0][r] = va.x; As[c4 + 1][r] = va.y;
      As[c4 + 2][r] = va.z; As[c4 + 3][r] = va.w;
    }
#pragma unroll
    for (int i = 0; i < 2; ++i) {
      int q = tid + i * 256;
      int r = q >> 5, c = (q & 31) << 2;
      *(float4*)(&Bs[r][c]) = *(const float4*)(B + (size_t)(k0 + r) * 512 + bn + c);
    }
    __syncthreads();
#pragma unroll
    for (int kk = 0; kk < GBK; ++kk) {
      float4 a0 = *(const float4*)(&As[kk][tm * 8]);
      float4 a1 = *(const float4*)(&As[kk][tm * 8 + 4]);
      float4 b0 = *(const float4*)(&Bs[kk][tn * 8]);
      float4 b1 = *(const float4*)(&Bs[kk][tn * 8 + 4]);
      float av[8] = {a0.x, a0.y, a0.z, a0.w, a1.x, a1.y, a1.z, a1.w};
      float bv[8] = {b0.x, b0.y, b0.z, b0.w, b1.x, b1.y, b1.z, b1.w};
#pragma unroll
      for (int i = 0; i < 8; ++i)
#pragma unroll
        for (int jj = 0; jj < 8; ++jj)
          acc[i][jj] = fmaf(av[i], bv[jj], acc[i][jj]);
    }
    __syncthreads();
  }
#pragma unroll
  for (int jj = 0; jj < 8; ++jj) {
    int n = bn + tn * 8 + jj;
    float bb = bp[n];
    float4 v0 = make_float4(acc[0][jj] - bb, acc[1][jj] - bb, acc[2][jj] - bb, acc[3][jj] - bb);
    float4 v1 = make_float4(acc[4][jj] - bb, acc[5][jj] - bb, acc[6][jj] - bb, acc[7][jj] - bb);
    float* cp = C + (size_t)n * 16384 + bm + tm * 8;
    *(float4*)cp = v0;
    *(float4*)(cp + 4) = v1;
  }
}

// ---- merge-path sort + diff (bank-swizzled LDS) ----
// co-rank: smallest i in [max(0,so-L), min(so,L)] s.t. merged prefix of size
// so takes i from A, so-i from B. Convention: advance while A[i] < B[so-1-i].
__device__ inline int corank(const float* __restrict__ s, int pb, int L, int so) {
  int lo = so - L; lo = lo < 0 ? 0 : lo;
  int hi = so < L ? so : L;
  while (lo < hi) {
    int mid = (lo + hi) >> 1;
    float a = s[SIDX(pb + mid)];
    float b = s[SIDX(pb + L + so - 1 - mid)];
    if (a < b) lo = mid + 1; else hi = mid;
  }
  return lo;
}

// One merge-path round: v holds this thread's 16 values of a sorted run of
// length L; after the call v holds its 16 values of the merged 2L run.
// crosswave=false (L<=512): window 2L fits in this wave's 1024-elem segment,
// no block barrier needed (wave64 lockstep + in-order DS pipe).
// crosswave=true: write;sync;read;sync.
__device__ __forceinline__ void merge_round(float (&v)[16], float* __restrict__ s,
                                            int t, int bi, int L, bool crosswave) {
  // staging: this thread's 16 elements share one 32-row -> constant XOR;
  // addresses are a permuted contiguous 16-block (conflict-free).
  int sw = (bi >> 5) & 31;
#pragma unroll
  for (int q = 0; q < 16; ++q) s[(bi + q) ^ sw] = v[q];
  if (crosswave) __syncthreads();
  else __builtin_amdgcn_wave_barrier();
  int pb = bi & ~(2 * L - 1);
  int so = bi - pb;
  int i0 = corank(s, pb, L, so);
  int nxt = __shfl_down(i0, 1, 64);   // lane t+1's i0 == our i1
  int i1;
  if (((so + 16) & (2 * L - 1)) == 0) i1 = L;              // last window slot
  else if (crosswave && (t & 63) == 63) i1 = corank(s, pb, L, so + 16);
  else i1 = nxt;
  int na = i1 - i0;
  int j1 = so + 16 - i1;
#pragma unroll
  for (int q = 0; q < 16; ++q) {
    int idx = (q < na) ? (pb + i0 + q)
                       : (pb + L + j1 - 1 - (q - na));
    v[q] = s[SIDX(idx)];
  }
  // window = ascending A-part then descending B-part => bitonic; merge up
#pragma unroll
  for (int j = 8; j >= 1; j >>= 1) {
#pragma unroll
    for (int q = 0; q < 16; ++q) {
      if ((q & j) == 0) {
        float a = v[q], b = v[q | j];
        v[q] = fminf(a, b);
        v[q | j] = fmaxf(a, b);
      }
    }
  }
  if (crosswave) __syncthreads();
}

// full 16384-element sort of one column (entry: v = 16 ascending-sorted
// values at positions bi..bi+15). Exits with all threads synced.
__device__ __forceinline__ void mergesort_col(float (&v)[16], float* __restrict__ s,
                                              int t, int bi) {
  for (int L = 16; L <= 512; L <<= 1) merge_round(v, s, t, bi, L, false);
  for (int L = 1024; L <= 8192; L <<= 1) merge_round(v, s, t, bi, L, true);
}

__global__ __launch_bounds__(1024, 8) void sortdiff_kernel(
    const float* __restrict__ proj1, const float* __restrict__ proj2,
    float* __restrict__ sum, int m) {
  __shared__ float s[16384];
  int t = threadIdx.x;
  int col = blockIdx.x;  // 0..511
  const float INF = __builtin_huge_valf();
  float va[16], vb[16];
  int bi = t << 4;

  const float* pa = proj1 + (size_t)col * 16384;
  const float* pbp = proj2 + (size_t)col * 16384;
  if (bi < m) {
#pragma unroll
    for (int i = 0; i < 4; ++i) {
      float4 A4 = *(const float4*)(pa + bi + i * 4);
      va[i * 4 + 0] = A4.x; va[i * 4 + 1] = A4.y;
      va[i * 4 + 2] = A4.z; va[i * 4 + 3] = A4.w;
      float4 B4 = *(const float4*)(pbp + bi + i * 4);
      vb[i * 4 + 0] = B4.x; vb[i * 4 + 1] = B4.y;
      vb[i * 4 + 2] = B4.z; vb[i * 4 + 3] = B4.w;
    }
  } else {
#pragma unroll
    for (int r = 0; r < 16; ++r) { va[r] = INF; vb[r] = INF; }
  }

  // ---- in-thread bitonic-16 sort, both columns interleaved (2x ILP)
#pragma unroll
  for (int k = 2; k <= 16; k <<= 1) {
#pragma unroll
    for (int j = k >> 1; j >= 1; j >>= 1) {
#pragma unroll
      for (int r = 0; r < 16; ++r) {
        if ((r & j) == 0) {
          bool up = ((r & k) == 0);   // k=16: always true for r<16
          float a0 = va[r], b0 = va[r | j];
          float lo0 = fminf(a0, b0), hi0 = fmaxf(a0, b0);
          va[r] = up ? lo0 : hi0;
          va[r | j] = up ? hi0 : lo0;
          float a1 = vb[r], b1 = vb[r | j];
          float lo1 = fminf(a1, b1), hi1 = fmaxf(a1, b1);
          vb[r] = up ? lo1 : hi1;
          vb[r | j] = up ? hi1 : lo1;
        }
      }
    }
  }

  // column A: 10 merge-path rounds; result stays in va. exits synced.
  mergesort_col(va, s, t, bi);
  // column B: reuse LDS; result lands in vb.
  mergesort_col(vb, s, t, bi);

  float acc = 0.f;
  if (bi < m) {
#pragma unroll
    for (int q = 0; q < 16; ++q) acc += fabsf(va[q] - vb[q]);
  }

#pragma unroll
  for (int o = 32; o > 0; o >>= 1) acc += __shfl_down(acc, o, 64);
  if ((t & 63) == 0) s[t >> 6] = acc;
  __syncthreads();
  if (t == 0) {
    float tot = 0.f;
    for (int i = 0; i < 16; ++i) tot += s[i];
    atomicAdd(sum, tot);
  }
}

__global__ void final_kernel(const float* __restrict__ sums, float* __restrict__ out) {
  float r = sums[0] * (1.f / 8388608.f) + sums[1] * (1.f / 8388608.f) +
            sums[2] * (1.f / 8388608.f) + sums[3] * (1.f / 8388608.f) +
            sums[4] * (1.f / 6553600.f);
  out[0] = r * (1000.f / 5.f);
}

// ---------------------------------------------------------------------------

extern "C" void kernel_launch(void* const* d_in, const int* in_sizes, int n_in,
                              void* d_out, int out_size, void* d_ws, size_t ws_size,
                              hipStream_t stream) {
  const float* xin = (const float*)d_in[0];
  const float* yin = (const float*)d_in[1];
  float* out = (float*)d_out;

  char* base = (char*)d_ws;
  size_t off = 0;
  auto alloc = [&](size_t nfloats) -> float* {
    float* p = (float*)(base + off);
    off += ((nfloats * 4) + 255) & ~(size_t)255;
    return p;
  };
  float* gX[5];
  float* gY[5];
  gX[0] = (float*)xin;
  gY[0] = (float*)yin;
  gX[1] = alloc(6291456); gX[2] = alloc(1572864); gX[3] = alloc(393216); gX[4] = alloc(98304);
  gY[1] = alloc(6291456); gY[2] = alloc(1572864); gY[3] = alloc(393216); gY[4] = alloc(98304);
  float* p1 = alloc((size_t)16384 * 160);
  float* p2 = alloc((size_t)16384 * 160);
  float* rnd = alloc((size_t)5 * 75264);
  float* B1 = alloc(160 * 512);
  float* B2 = alloc(160 * 512);
  float* biasb = alloc(1024);
  float* proj1 = alloc((size_t)16384 * 512);
  float* proj2 = alloc((size_t)16384 * 512);
  float* part1 = alloc(ENB * 6);
  float* part2 = alloc(ENB * 6);
  float* misc = alloc(128);

  static const int Hs[5] = {256, 128, 64, 32, 16};

  Keys ks;
  for (int l = 0; l < 5; ++l) { ks.a[l] = g_tbl.kp0[l]; ks.b[l] = g_tbl.kp1[l]; }
  randgen_kernel<<<1470, 256, 0, stream>>>(rnd, ks, misc);

  // fused X+Y pyramid downsampling, level by level
  down_kernel<<<(2 * 384 * 128 * 128 + 255) / 256, 256, 0, stream>>>(
      xin, gX[1], yin, gY[1], 256, 256, 384 * 128 * 128);
  down_kernel<<<(2 * 384 * 64 * 64 + 255) / 256, 256, 0, stream>>>(
      gX[1], gX[2], gY[1], gY[2], 128, 128, 384 * 64 * 64);
  down_kernel<<<(2 * 384 * 32 * 32 + 255) / 256, 256, 0, stream>>>(
      gX[2], gX[3], gY[2], gY[3], 64, 64, 384 * 32 * 32);
  down_kernel<<<(2 * 384 * 16 * 16 + 255) / 256, 256, 0, stream>>>(
      gX[3], gX[4], gY[3], gY[4], 32, 32, 384 * 16 * 16);

  for (int l = 0; l < 5; ++l) {
    int H = Hs[l];
    int Wm6 = H - 6;
    int n = Wm6 * Wm6;
    int nd = n < 128 ? n : 128;
    int M = 128 * nd;
    int totalE = M * 160;
    extract_kernel<<<2 * ENB, 256, 0, stream>>>(
        gX[l], (l < 4) ? gX[l + 1] : nullptr, p1, part1,
        gY[l], (l < 4) ? gY[l + 1] : nullptr, p2, part2,
        g_tbl.rcs[l], H, nd, (l < 4) ? 1 : 0, totalE);
    prep_kernel<<<2, 256, 0, stream>>>(rnd + (size_t)l * 75264, part1, part2,
                                       B1, B2, biasb, (float)M * 49.f);
    dim3 gg(M / 128, 4, 2);
    gemm_kernel<<<gg, 256, 0, stream>>>(p1, B1, p2, B2, biasb, proj1, proj2, M);
    sortdiff_kernel<<<512, 1024, 0, stream>>>(proj1, proj2, misc + l, M);
  }
  final_kernel<<<1, 1, 0, stream>>>(misc, out);
}

// Round 8
// 1760.010 us; speedup vs baseline: 1.7878x; 1.1148x over previous
//
#include <hip/hip_runtime.h>
#include <hip/hip_bf16.h>
#include <cstdint>
#include <cmath>
#include <vector>
#include <algorithm>
#include <numeric>

// ---------------------------------------------------------------------------
// LapSWD loss. RNG = exact JAX partitionable threefry.
// R13: down_kernel rewritten as LDS-tiled SEPARABLE 5-tap pyramid convolution.
// Old form: 25 scalar stride-2 global loads + ~600 VALU per output -> 963 GB/s
// (12% peak) at 88% occupancy, 233us for a 225MB-traffic dispatch (min ~36us).
// New form: per block, stage (2*TR+3) full-width input rows via coalesced
// float4 (zero OOB rows), horizontal 5-tap into LDS hbuf (stride-2 LDS reads
// = 2 lanes/bank = free), vertical 5-tap to global. ~3 vec loads + ~115 VALU
// per thread for 2 outputs. All index math is shifts (W, Wo, TR, nby pow2).
// NOTE: separable order changes FP rounding vs the direct 25-term sum; absmax
// may leave exactly-0.0 but stays ~1e-5 against threshold 3.74.
// Rest identical to R12 (merge-path sortdiff + swizzle, atomic-free extract,
// fused X+Y dispatches).
// ---------------------------------------------------------------------------

#define SIDX(i) ((i) ^ (((i) >> 5) & 31))
#define ENB 2048  // extract grid per half: 2048 blocks x 256 thr, grid-stride

struct RC { unsigned int rc[128]; };
struct Keys { uint32_t a[5]; uint32_t b[5]; };

// ---- threefry2x32 block cipher, exact JAX/XLA schedule ----
__host__ __device__ inline void tf2x32(uint32_t k0, uint32_t k1,
                                       uint32_t x0, uint32_t x1,
                                       uint32_t& o0, uint32_t& o1) {
  uint32_t k2 = k0 ^ k1 ^ 0x1BD11BDAu;
  x0 += k0; x1 += k1;
#define TFR(r) { x0 += x1; x1 = (x1 << r) | (x1 >> (32 - r)); x1 ^= x0; }
  TFR(13) TFR(15) TFR(26) TFR(6)   x0 += k1; x1 += k2 + 1u;
  TFR(17) TFR(29) TFR(16) TFR(24)  x0 += k2; x1 += k0 + 2u;
  TFR(13) TFR(15) TFR(26) TFR(6)   x0 += k0; x1 += k1 + 3u;
  TFR(17) TFR(29) TFR(16) TFR(24)  x0 += k1; x1 += k2 + 4u;
  TFR(13) TFR(15) TFR(26) TFR(6)   x0 += k2; x1 += k0 + 5u;
#undef TFR
  o0 = x0; o1 = x1;
}

// ---- host tables (pure constants; computed once at library load) ----
struct HostTables {
  RC rcs[5];
  uint32_t kp0[5], kp1[5];
  HostTables() {
    static const int Hs[5] = {256, 128, 64, 32, 16};
    for (int l = 0; l < 5; ++l) {
      uint32_t f0, f1;
      tf2x32(0u, 42u, 0u, (uint32_t)l, f0, f1);  // fold_in(key(42), l)
      uint32_t ik0, ik1;
      tf2x32(f0, f1, 0u, 0u, ik0, ik1);          // k_idx = split[0]
      tf2x32(f0, f1, 0u, 1u, kp0[l], kp1[l]);    // k_proj = split[1]
      int Wm6 = Hs[l] - 6;
      int n = Wm6 * Wm6;
      int nd = n < 128 ? n : 128;
      std::vector<int> perm(n);
      std::iota(perm.begin(), perm.end(), 0);
      int rounds = (int)std::ceil(3.0 * std::log((double)n) / std::log(4294967295.0));
      uint32_t key0 = ik0, key1 = ik1;
      std::vector<uint32_t> bits(n);
      std::vector<int> ord(n), tmp(n);
      for (int r = 0; r < rounds; ++r) {
        uint32_t nk0, nk1, s0, s1;
        tf2x32(key0, key1, 0u, 0u, nk0, nk1);
        tf2x32(key0, key1, 0u, 1u, s0, s1);
        key0 = nk0; key1 = nk1;
        for (int tt = 0; tt < n; ++tt) {
          uint32_t o0, o1;
          tf2x32(s0, s1, 0u, (uint32_t)tt, o0, o1);
          bits[tt] = o0 ^ o1;
        }
        std::iota(ord.begin(), ord.end(), 0);
        std::stable_sort(ord.begin(), ord.end(),
                         [&](int A, int B) { return bits[A] < bits[B]; });
        for (int i2 = 0; i2 < n; ++i2) tmp[i2] = perm[ord[i2]];
        perm.swap(tmp);
      }
      for (int d = 0; d < 128; ++d) {
        int vv = (d < nd) ? perm[d] : 0;
        rcs[l].rc[d] = ((uint32_t)(vv / Wm6) << 16) | (uint32_t)(vv % Wm6);
      }
    }
  }
};
static const HostTables g_tbl;

__device__ inline float erfinv_f(float x) {
  float w = -log1pf(-x * x);
  float p;
  if (w < 5.0f) {
    w = w - 2.5f;
    p = 2.81022636e-08f;
    p = fmaf(p, w, 3.43273939e-07f);
    p = fmaf(p, w, -3.5233877e-06f);
    p = fmaf(p, w, -4.39150654e-06f);
    p = fmaf(p, w, 0.00021858087f);
    p = fmaf(p, w, -0.00125372503f);
    p = fmaf(p, w, -0.00417768164f);
    p = fmaf(p, w, 0.246640727f);
    p = fmaf(p, w, 1.50140941f);
  } else {
    w = sqrtf(w) - 3.0f;
    p = -0.000200214257f;
    p = fmaf(p, w, 0.000100950558f);
    p = fmaf(p, w, 0.00134934322f);
    p = fmaf(p, w, -0.00367342844f);
    p = fmaf(p, w, 0.00573950773f);
    p = fmaf(p, w, -0.0076224613f);
    p = fmaf(p, w, 0.00943887047f);
    p = fmaf(p, w, 1.00167406f);
    p = fmaf(p, w, 2.83297682f);
  }
  return p * x;
}

__device__ inline float bits_to_normal(uint32_t b) {
  union { uint32_t u; float f; } cv;
  cv.u = (b >> 9) | 0x3f800000u;
  float f = cv.f - 1.0f;
  const float lo = -0.99999994f;
  const float span = 1.0f - lo;
  float u = fmaxf(lo, __fadd_rn(__fmul_rn(f, span), lo));
  return 1.41421356237f * erfinv_f(u);
}

// ---- kernels ----

// LDS-tiled separable 5x5 binomial downsample (stride 2, zero-pad 2).
// One block: TR output rows x full output width Wo, for one (side,bc,by).
// ltr = log2(TR), lgW = log2(W). W,H square. TR*Wo <= 512, rows=2*TR+3.
__global__ __launch_bounds__(256) void down_kernel(
    const float* __restrict__ inX, float* __restrict__ outX,
    const float* __restrict__ inY, float* __restrict__ outY,
    int H, int ltr, int lgW) {
  __shared__ __align__(16) float si[2816];  // max 11*256 (L1)
  __shared__ float hb[1408];                // max 11*128 (L1)
  int W = 1 << lgW;
  int lgWo = lgW - 1;
  int Wo = W >> 1, Ho = H >> 1;
  int TR = 1 << ltr;
  int lgnby = lgWo - ltr;                   // nby = Ho/TR (pow2)
  int nby = 1 << lgnby;
  int per = 384 << lgnby;
  int bid = blockIdx.x;
  const float* in = inX; float* out = outX;
  if (bid >= per) { bid -= per; in = inY; out = outY; }
  int bc = bid >> lgnby;
  int by = bid & (nby - 1);
  int oy0 = by << ltr;
  int rows = 2 * TR + 3;
  int y0 = 2 * oy0 - 2;
  const float* src = in + (size_t)bc * H * W;
  int t = threadIdx.x;

  // stage input rows [y0, y0+rows) full-width; zero OOB rows (zero-pad)
  int nf4 = (rows << lgW) >> 2;
  for (int i = t; i < nf4; i += 256) {
    int fi = i << 2;
    int r = fi >> lgW, x = fi & (W - 1);
    int y = y0 + r;
    float4 v = (y >= 0 && y < H) ? *(const float4*)(src + ((size_t)y << lgW) + x)
                                 : make_float4(0.f, 0.f, 0.f, 0.f);
    *(float4*)(si + fi) = v;
  }
  __syncthreads();

  // horizontal 5-tap at stride 2 (zero-pad x edges)
  int nh = rows << lgWo;
  for (int i = t; i < nh; i += 256) {
    int r = i >> lgWo, ox = i & (Wo - 1);
    const float* rp = si + (r << lgW);
    int xb = 2 * ox;
    float s = 0.375f * rp[xb] + 0.25f * rp[xb + 1];
    if (ox >= 1) s += 0.0625f * rp[xb - 2] + 0.25f * rp[xb - 1];
    if (xb + 2 < W) s += 0.0625f * rp[xb + 2];
    hb[i] = s;
  }
  __syncthreads();

  // vertical 5-tap: out row oy0+r uses hb rows 2r..2r+4
  int no = TR << lgWo;
  float* dst = out + (size_t)bc * Ho * Wo;
  for (int i = t; i < no; i += 256) {
    int r = i >> lgWo, ox = i & (Wo - 1);
    const float* cp = hb + ((2 * r) << lgWo) + ox;
    float s = 0.0625f * cp[0] + 0.25f * cp[Wo] + 0.375f * cp[2 * Wo] +
              0.25f * cp[3 * Wo] + 0.0625f * cp[4 * Wo];
    dst[((size_t)(oy0 + r) << lgWo) + ox] = s;
  }
}

// all 5 levels' random projection bits in one dispatch; block 0 also zeroes misc
__global__ void randgen_kernel(float* __restrict__ rnd, Keys ks,
                               float* __restrict__ misc) {
  int t = blockIdx.x * 256 + threadIdx.x;   // 1470 blocks = 376320 = 5*75264
  if (blockIdx.x == 0 && threadIdx.x < 128) misc[threadIdx.x] = 0.f;
  const int per = 75264;                    // 147*512
  int l = t / per;
  int tt = t - l * per;
  if (l < 5) {
    uint32_t o0, o1;
    tf2x32(ks.a[l], ks.b[l], 0u, (uint32_t)tt, o0, o1);
    rnd[l * per + tt] = bits_to_normal(o0 ^ o1);
  }
}

// extract + per-channel stats (sum, sumsq); X and Y halves in one dispatch;
// grid-stride per half, per-block partials -- NO global atomics.
__global__ __launch_bounds__(256) void extract_kernel(
    const float* __restrict__ g1, const float* __restrict__ gn1,
    float* __restrict__ p1g, float* __restrict__ part1,
    const float* __restrict__ g2, const float* __restrict__ gn2,
    float* __restrict__ p2g, float* __restrict__ part2,
    RC rcs, int H, int nd, int useLap, int total) {
  __shared__ float ls[6];
  if (threadIdx.x < 6) ls[threadIdx.x] = 0.f;
  __syncthreads();
  int half = (blockIdx.x >= ENB) ? 1 : 0;
  int bid = blockIdx.x - half * ENB;
  const float* g = half ? g2 : g1;
  const float* gn = half ? gn2 : gn1;
  float* p = half ? p2g : p1g;
  float* part = half ? part2 : part1;
  for (int idx = bid * 256 + threadIdx.x; idx < total; idx += ENB * 256) {
    int col = idx % 160;
    if (col < 147) {
      int row = idx / 160;
      int d = row % nd, b = row / nd;
      int c = col / 49, uv = col % 49, u = uv / 7, v = uv % 7;
      unsigned rc = rcs.rc[d];
      int y = (int)(rc >> 16) + u;
      int x = (int)(rc & 0xffffu) + v;
      const float* gc = g + ((size_t)(b * 3 + c)) * H * H;
      float val = gc[(size_t)y * H + x];
      if (useLap) {
        int H2 = H >> 1;
        const float* gnc = gn + ((size_t)(b * 3 + c)) * H2 * H2;
        int h = y >> 1, w = x >> 1;
        int yo = y & 1, xo = x & 1;
        float rw0 = (y >= 2) ? (yo ? 0.0625f : 0.3125f) : 0.f;
        float rw2 = (y <= H - 3) ? (yo ? 0.3125f : 0.0625f) : 0.f;
        float cw0 = (x >= 2) ? (xo ? 0.0625f : 0.3125f) : 0.f;
        float cw2 = (x <= H - 3) ? (xo ? 0.3125f : 0.0625f) : 0.f;
        int r0 = max(h - 1, 0), r2 = min(h + 1, H2 - 1);
        int c0 = max(w - 1, 0), c2 = min(w + 1, H2 - 1);
        const float* R0 = gnc + (size_t)r0 * H2;
        const float* R1 = gnc + (size_t)h * H2;
        const float* R2 = gnc + (size_t)r2 * H2;
        float s0 = cw0 * R0[c0] + 0.625f * R0[w] + cw2 * R0[c2];
        float s1 = cw0 * R1[c0] + 0.625f * R1[w] + cw2 * R1[c2];
        float s2 = cw0 * R2[c0] + 0.625f * R2[w] + cw2 * R2[c2];
        val -= rw0 * s0 + 0.625f * s1 + rw2 * s2;
      }
      p[idx] = val;
      atomicAdd(&ls[c], val);
      atomicAdd(&ls[3 + c], val * val);
    }
  }
  __syncthreads();
  if (threadIdx.x < 6) part[bid * 6 + threadIdx.x] = ls[threadIdx.x];
}

// reduce ENB-block partials, then build projection matrices + bias
__global__ void prep_kernel(const float* __restrict__ rnd,
                            const float* __restrict__ part1,
                            const float* __restrict__ part2,
                            float* __restrict__ B1, float* __restrict__ B2,
                            float* __restrict__ bias, float Np) {
  __shared__ float red[12];
  int tid = threadIdx.x;
  if (tid < 12) red[tid] = 0.f;
  __syncthreads();
  if (tid < 192) {
    int k = tid >> 4, r0 = tid & 15;        // 12 groups x 16 threads; 2048%16==0
    const float* src = (k < 6) ? part1 : part2;
    int kk = (k < 6) ? k : k - 6;
    float ssum = 0.f;
    for (int r = r0; r < ENB; r += 16) ssum += src[r * 6 + kk];
    atomicAdd(&red[k], ssum);
  }
  __syncthreads();
  int j = blockIdx.x * 256 + tid;
  if (j >= 512) return;
  float sum = 0.f, q = 0.f;
  for (int f = 0; f < 147; ++f) {
    float v = rnd[f * 512 + j];
    sum += v; q = fmaf(v, v, q);
  }
  float mean = sum * (1.f / 147.f);
  float var = (q - 147.f * mean * mean) * (1.f / 146.f);
  float inv1 = 1.f / sqrtf(var);
  float b1 = 0.f, b2 = 0.f;
#pragma unroll
  for (int c = 0; c < 3; ++c) {
    float m1 = red[c] / Np;
    float v1 = (red[3 + c] - Np * m1 * m1) / (Np - 1.f);
    float i1 = 1.f / (sqrtf(fmaxf(v1, 0.f)) + 1e-8f);
    float m2 = red[6 + c] / Np;
    float v2 = (red[9 + c] - Np * m2 * m2) / (Np - 1.f);
    float i2 = 1.f / (sqrtf(fmaxf(v2, 0.f)) + 1e-8f);
    for (int ff = 0; ff < 49; ++ff) {
      int f = c * 49 + ff;
      float rv = rnd[f * 512 + j] * inv1;
      float w1 = rv * i1; B1[f * 512 + j] = w1; b1 = fmaf(m1, w1, b1);
      float w2 = rv * i2; B2[f * 512 + j] = w2; b2 = fmaf(m2, w2, b2);
    }
  }
  for (int f = 147; f < 160; ++f) { B1[f * 512 + j] = 0.f; B2[f * 512 + j] = 0.f; }
  bias[j] = b1; bias[512 + j] = b2;
}

// C[n][m] col-major (stride 16384) = A[M][160] * B[160][512] - bias[n]
// blockIdx.z selects (p1,B1,bias,proj1) vs (p2,B2,bias+512,proj2)
#define GBM 128
#define GBN 128
#define GBK 16
__global__ __launch_bounds__(256) void gemm_kernel(
    const float* __restrict__ A1, const float* __restrict__ Bm1,
    const float* __restrict__ A2, const float* __restrict__ Bm2,
    const float* __restrict__ bias, float* __restrict__ C1,
    float* __restrict__ C2, int M) {
  __shared__ __align__(16) float As[GBK][GBM + 4];
  __shared__ __align__(16) float Bs[GBK][GBN];
  int z = blockIdx.z;
  const float* A = z ? A2 : A1;
  const float* B = z ? Bm2 : Bm1;
  const float* bp = bias + (z ? 512 : 0);
  float* C = z ? C2 : C1;
  int bm = blockIdx.x * GBM;
  int bn = blockIdx.y * GBN;
  int tid = threadIdx.x;
  int tm = tid & 15;
  int tn = tid >> 4;
  float acc[8][8] = {{0.f}};
  for (int k0 = 0; k0 < 160; k0 += GBK) {
#pragma unroll
    for (int i = 0; i < 2; ++i) {
      int q = tid + i * 256;
      int r = q >> 2, c4 = (q & 3) << 2;
      float4 va = *(const float4*)(A + (size_t)(bm + r) * 160 + k0 + c4);
      As[c4 + 0][r] = va.x; As[c4 + 1][r] = va.y;
      As[c4 + 2][r] = va.z; As[c4 + 3][r] = va.w;
    }
#pragma unroll
    for (int i = 0; i < 2; ++i) {
      int q = tid + i * 256;
      int r = q >> 5, c = (q & 31) << 2;
      *(float4*)(&Bs[r][c]) = *(const float4*)(B + (size_t)(k0 + r) * 512 + bn + c);
    }
    __syncthreads();
#pragma unroll
    for (int kk = 0; kk < GBK; ++kk) {
      float4 a0 = *(const float4*)(&As[kk][tm * 8]);
      float4 a1 = *(const float4*)(&As[kk][tm * 8 + 4]);
      float4 b0 = *(const float4*)(&Bs[kk][tn * 8]);
      float4 b1 = *(const float4*)(&Bs[kk][tn * 8 + 4]);
      float av[8] = {a0.x, a0.y, a0.z, a0.w, a1.x, a1.y, a1.z, a1.w};
      float bv[8] = {b0.x, b0.y, b0.z, b0.w, b1.x, b1.y, b1.z, b1.w};
#pragma unroll
      for (int i = 0; i < 8; ++i)
#pragma unroll
        for (int jj = 0; jj < 8; ++jj)
          acc[i][jj] = fmaf(av[i], bv[jj], acc[i][jj]);
    }
    __syncthreads();
  }
#pragma unroll
  for (int jj = 0; jj < 8; ++jj) {
    int n = bn + tn * 8 + jj;
    float bb = bp[n];
    float4 v0 = make_float4(acc[0][jj] - bb, acc[1][jj] - bb, acc[2][jj] - bb, acc[3][jj] - bb);
    float4 v1 = make_float4(acc[4][jj] - bb, acc[5][jj] - bb, acc[6][jj] - bb, acc[7][jj] - bb);
    float* cp = C + (size_t)n * 16384 + bm + tm * 8;
    *(float4*)cp = v0;
    *(float4*)(cp + 4) = v1;
  }
}

// ---- merge-path sort + diff (bank-swizzled LDS) ----
// co-rank: smallest i in [max(0,so-L), min(so,L)] s.t. merged prefix of size
// so takes i from A, so-i from B. Convention: advance while A[i] < B[so-1-i].
__device__ inline int corank(const float* __restrict__ s, int pb, int L, int so) {
  int lo = so - L; lo = lo < 0 ? 0 : lo;
  int hi = so < L ? so : L;
  while (lo < hi) {
    int mid = (lo + hi) >> 1;
    float a = s[SIDX(pb + mid)];
    float b = s[SIDX(pb + L + so - 1 - mid)];
    if (a < b) lo = mid + 1; else hi = mid;
  }
  return lo;
}

// One merge-path round: v holds this thread's 16 values of a sorted run of
// length L; after the call v holds its 16 values of the merged 2L run.
// crosswave=false (L<=512): window 2L fits in this wave's 1024-elem segment,
// no block barrier needed (wave64 lockstep + in-order DS pipe).
// crosswave=true: write;sync;read;sync.
__device__ __forceinline__ void merge_round(float (&v)[16], float* __restrict__ s,
                                            int t, int bi, int L, bool crosswave) {
  // staging: this thread's 16 elements share one 32-row -> constant XOR;
  // addresses are a permuted contiguous 16-block (conflict-free).
  int sw = (bi >> 5) & 31;
#pragma unroll
  for (int q = 0; q < 16; ++q) s[(bi + q) ^ sw] = v[q];
  if (crosswave) __syncthreads();
  else __builtin_amdgcn_wave_barrier();
  int pb = bi & ~(2 * L - 1);
  int so = bi - pb;
  int i0 = corank(s, pb, L, so);
  int nxt = __shfl_down(i0, 1, 64);   // lane t+1's i0 == our i1
  int i1;
  if (((so + 16) & (2 * L - 1)) == 0) i1 = L;              // last window slot
  else if (crosswave && (t & 63) == 63) i1 = corank(s, pb, L, so + 16);
  else i1 = nxt;
  int na = i1 - i0;
  int j1 = so + 16 - i1;
#pragma unroll
  for (int q = 0; q < 16; ++q) {
    int idx = (q < na) ? (pb + i0 + q)
                       : (pb + L + j1 - 1 - (q - na));
    v[q] = s[SIDX(idx)];
  }
  // window = ascending A-part then descending B-part => bitonic; merge up
#pragma unroll
  for (int j = 8; j >= 1; j >>= 1) {
#pragma unroll
    for (int q = 0; q < 16; ++q) {
      if ((q & j) == 0) {
        float a = v[q], b = v[q | j];
        v[q] = fminf(a, b);
        v[q | j] = fmaxf(a, b);
      }
    }
  }
  if (crosswave) __syncthreads();
}

// full 16384-element sort of one column (entry: v = 16 ascending-sorted
// values at positions bi..bi+15). Exits with all threads synced.
__device__ __forceinline__ void mergesort_col(float (&v)[16], float* __restrict__ s,
                                              int t, int bi) {
  for (int L = 16; L <= 512; L <<= 1) merge_round(v, s, t, bi, L, false);
  for (int L = 1024; L <= 8192; L <<= 1) merge_round(v, s, t, bi, L, true);
}

__global__ __launch_bounds__(1024, 8) void sortdiff_kernel(
    const float* __restrict__ proj1, const float* __restrict__ proj2,
    float* __restrict__ sum, int m) {
  __shared__ float s[16384];
  int t = threadIdx.x;
  int col = blockIdx.x;  // 0..511
  const float INF = __builtin_huge_valf();
  float va[16], vb[16];
  int bi = t << 4;

  const float* pa = proj1 + (size_t)col * 16384;
  const float* pbp = proj2 + (size_t)col * 16384;
  if (bi < m) {
#pragma unroll
    for (int i = 0; i < 4; ++i) {
      float4 A4 = *(const float4*)(pa + bi + i * 4);
      va[i * 4 + 0] = A4.x; va[i * 4 + 1] = A4.y;
      va[i * 4 + 2] = A4.z; va[i * 4 + 3] = A4.w;
      float4 B4 = *(const float4*)(pbp + bi + i * 4);
      vb[i * 4 + 0] = B4.x; vb[i * 4 + 1] = B4.y;
      vb[i * 4 + 2] = B4.z; vb[i * 4 + 3] = B4.w;
    }
  } else {
#pragma unroll
    for (int r = 0; r < 16; ++r) { va[r] = INF; vb[r] = INF; }
  }

  // ---- in-thread bitonic-16 sort, both columns interleaved (2x ILP)
#pragma unroll
  for (int k = 2; k <= 16; k <<= 1) {
#pragma unroll
    for (int j = k >> 1; j >= 1; j >>= 1) {
#pragma unroll
      for (int r = 0; r < 16; ++r) {
        if ((r & j) == 0) {
          bool up = ((r & k) == 0);   // k=16: always true for r<16
          float a0 = va[r], b0 = va[r | j];
          float lo0 = fminf(a0, b0), hi0 = fmaxf(a0, b0);
          va[r] = up ? lo0 : hi0;
          va[r | j] = up ? hi0 : lo0;
          float a1 = vb[r], b1 = vb[r | j];
          float lo1 = fminf(a1, b1), hi1 = fmaxf(a1, b1);
          vb[r] = up ? lo1 : hi1;
          vb[r | j] = up ? hi1 : lo1;
        }
      }
    }
  }

  // column A: 10 merge-path rounds; result stays in va. exits synced.
  mergesort_col(va, s, t, bi);
  // column B: reuse LDS; result lands in vb.
  mergesort_col(vb, s, t, bi);

  float acc = 0.f;
  if (bi < m) {
#pragma unroll
    for (int q = 0; q < 16; ++q) acc += fabsf(va[q] - vb[q]);
  }

#pragma unroll
  for (int o = 32; o > 0; o >>= 1) acc += __shfl_down(acc, o, 64);
  if ((t & 63) == 0) s[t >> 6] = acc;
  __syncthreads();
  if (t == 0) {
    float tot = 0.f;
    for (int i = 0; i < 16; ++i) tot += s[i];
    atomicAdd(sum, tot);
  }
}

__global__ void final_kernel(const float* __restrict__ sums, float* __restrict__ out) {
  float r = sums[0] * (1.f / 8388608.f) + sums[1] * (1.f / 8388608.f) +
            sums[2] * (1.f / 8388608.f) + sums[3] * (1.f / 8388608.f) +
            sums[4] * (1.f / 6553600.f);
  out[0] = r * (1000.f / 5.f);
}

// ---------------------------------------------------------------------------

extern "C" void kernel_launch(void* const* d_in, const int* in_sizes, int n_in,
                              void* d_out, int out_size, void* d_ws, size_t ws_size,
                              hipStream_t stream) {
  const float* xin = (const float*)d_in[0];
  const float* yin = (const float*)d_in[1];
  float* out = (float*)d_out;

  char* base = (char*)d_ws;
  size_t off = 0;
  auto alloc = [&](size_t nfloats) -> float* {
    float* p = (float*)(base + off);
    off += ((nfloats * 4) + 255) & ~(size_t)255;
    return p;
  };
  float* gX[5];
  float* gY[5];
  gX[0] = (float*)xin;
  gY[0] = (float*)yin;
  gX[1] = alloc(6291456); gX[2] = alloc(1572864); gX[3] = alloc(393216); gX[4] = alloc(98304);
  gY[1] = alloc(6291456); gY[2] = alloc(1572864); gY[3] = alloc(393216); gY[4] = alloc(98304);
  float* p1 = alloc((size_t)16384 * 160);
  float* p2 = alloc((size_t)16384 * 160);
  float* rnd = alloc((size_t)5 * 75264);
  float* B1 = alloc(160 * 512);
  float* B2 = alloc(160 * 512);
  float* biasb = alloc(1024);
  float* proj1 = alloc((size_t)16384 * 512);
  float* proj2 = alloc((size_t)16384 * 512);
  float* part1 = alloc(ENB * 6);
  float* part2 = alloc(ENB * 6);
  float* misc = alloc(128);

  static const int Hs[5] = {256, 128, 64, 32, 16};

  Keys ks;
  for (int l = 0; l < 5; ++l) { ks.a[l] = g_tbl.kp0[l]; ks.b[l] = g_tbl.kp1[l]; }
  randgen_kernel<<<1470, 256, 0, stream>>>(rnd, ks, misc);

  // fused X+Y separable pyramid downsampling:
  // L1: TR=4  -> nby=32, blocks=2*384*32; L2: TR=8 -> nby=8;
  // L3: TR=16 -> nby=2;  L4: TR=16(=Ho) -> nby=1.
  down_kernel<<<2 * 384 * 32, 256, 0, stream>>>(xin, gX[1], yin, gY[1], 256, 2, 8);
  down_kernel<<<2 * 384 * 8, 256, 0, stream>>>(gX[1], gX[2], gY[1], gY[2], 128, 3, 7);
  down_kernel<<<2 * 384 * 2, 256, 0, stream>>>(gX[2], gX[3], gY[2], gY[3], 64, 4, 6);
  down_kernel<<<2 * 384 * 1, 256, 0, stream>>>(gX[3], gX[4], gY[3], gY[4], 32, 4, 5);

  for (int l = 0; l < 5; ++l) {
    int H = Hs[l];
    int Wm6 = H - 6;
    int n = Wm6 * Wm6;
    int nd = n < 128 ? n : 128;
    int M = 128 * nd;
    int totalE = M * 160;
    extract_kernel<<<2 * ENB, 256, 0, stream>>>(
        gX[l], (l < 4) ? gX[l + 1] : nullptr, p1, part1,
        gY[l], (l < 4) ? gY[l + 1] : nullptr, p2, part2,
        g_tbl.rcs[l], H, nd, (l < 4) ? 1 : 0, totalE);
    prep_kernel<<<2, 256, 0, stream>>>(rnd + (size_t)l * 75264, part1, part2,
                                       B1, B2, biasb, (float)M * 49.f);
    dim3 gg(M / 128, 4, 2);
    gemm_kernel<<<gg, 256, 0, stream>>>(p1, B1, p2, B2, biasb, proj1, proj2, M);
    sortdiff_kernel<<<512, 1024, 0, stream>>>(proj1, proj2, misc + l, M);
  }
  final_kernel<<<1, 1, 0, stream>>>(misc, out);
}